// Round 2
// baseline (9020.869 us; speedup 1.0000x reference)
//
#include <hip/hip_runtime.h>
#include <hip/hip_bf16.h>

#define M_TOK   8000
#define L_SEQ   2000
#define BATCH   4
#define NEXP    4
#define NH      16
#define HD      64
#define DSTATE  128
#define DMODEL  512
#define DINNER  1024
#define CONVD   1280
#define DIN_ALL 2320   // 1024 z + 1280 xBC + 16 dt

__device__ __forceinline__ float siluf(float v) {
    return v / (1.f + __expf(-v));
}
__device__ __forceinline__ float softplusf(float v) {
    return v > 20.f ? v : log1pf(expf(v));
}

// ---------------------------------------------------------------- gating ----
__global__ void __launch_bounds__(64) gate_kernel(
    const float* __restrict__ X,    // M x 512
    const float* __restrict__ GW,   // 4 x 512
    const float* __restrict__ GB,   // 4
    const float* __restrict__ GN,   // M x 4
    float* __restrict__ mask)       // M x 4
{
    const int m = blockIdx.x;
    const int t = threadIdx.x;
    const float* x = X + (size_t)m * DMODEL;
    float s0 = 0.f, s1 = 0.f, s2 = 0.f, s3 = 0.f;
    for (int k = t; k < DMODEL; k += 64) {
        float xv = x[k];
        s0 += xv * GW[k];
        s1 += xv * GW[512 + k];
        s2 += xv * GW[1024 + k];
        s3 += xv * GW[1536 + k];
    }
    #pragma unroll
    for (int o = 32; o > 0; o >>= 1) {
        s0 += __shfl_down(s0, o);
        s1 += __shfl_down(s1, o);
        s2 += __shfl_down(s2, o);
        s3 += __shfl_down(s3, o);
    }
    if (t == 0) {
        float lg[4] = { s0 + GB[0] + GN[m*4+0]*0.01f,
                        s1 + GB[1] + GN[m*4+1]*0.01f,
                        s2 + GB[2] + GN[m*4+2]*0.01f,
                        s3 + GB[3] + GN[m*4+3]*0.01f };
        float mx = fmaxf(fmaxf(lg[0], lg[1]), fmaxf(lg[2], lg[3]));
        float p[4]; float sum = 0.f;
        #pragma unroll
        for (int e = 0; e < 4; ++e) { p[e] = expf(lg[e] - mx); sum += p[e]; }
        #pragma unroll
        for (int e = 0; e < 4; ++e) p[e] /= sum;
        int i0 = 0;
        #pragma unroll
        for (int e = 1; e < 4; ++e) if (p[e] > p[i0]) i0 = e;
        int i1 = -1;
        #pragma unroll
        for (int e = 0; e < 4; ++e) {
            if (e == i0) continue;
            if (i1 < 0 || p[e] > p[i1]) i1 = e;
        }
        float s2v = p[i0] + p[i1];
        #pragma unroll
        for (int e = 0; e < 4; ++e)
            mask[m*4 + e] = (e == i0 || e == i1) ? p[e] / s2v : 0.f;
    }
}

// ------------------------------------------------------------ in_proj gemm --
// out = X(8000x512) @ Wi^T(2320x512) for ONE expert (pointers pre-offset),
// routed: z / xBC / softplus(dt+bias)
__global__ void __launch_bounds__(256) gemm_inproj(
    const float* __restrict__ X,
    const float* __restrict__ Wb,      // 2320 x 512 (expert slice)
    const float* __restrict__ dtb,     // 16        (expert slice)
    float* __restrict__ XBC,           // M x 1280  (expert slice)
    float* __restrict__ Z,             // M x 1024  (expert slice)
    float* __restrict__ DT)            // M x 16    (expert slice)
{
    const int m0 = blockIdx.y * 64;
    const int n0 = blockIdx.x * 64;
    const int t  = threadIdx.x;
    __shared__ float As[16][64];
    __shared__ float Bs[16][64];
    const int tm = t >> 4, tn = t & 15;
    const int lr = t >> 2;          // 0..63
    const int lk = (t & 3) * 4;     // 0,4,8,12
    float acc[4][4] = {};

    for (int k0 = 0; k0 < DMODEL; k0 += 16) {
        float4 av = *(const float4*)(X + (size_t)(m0 + lr) * DMODEL + k0 + lk);
        int nrow = n0 + lr;
        float4 bv = make_float4(0.f, 0.f, 0.f, 0.f);
        if (nrow < DIN_ALL)
            bv = *(const float4*)(Wb + (size_t)nrow * DMODEL + k0 + lk);
        #pragma unroll
        for (int j = 0; j < 4; ++j) {
            As[lk + j][lr] = ((const float*)&av)[j];
            Bs[lk + j][lr] = ((const float*)&bv)[j];
        }
        __syncthreads();
        #pragma unroll
        for (int kk = 0; kk < 16; ++kk) {
            float4 a4 = *(const float4*)&As[kk][tm*4];
            float4 b4 = *(const float4*)&Bs[kk][tn*4];
            const float* ap = (const float*)&a4;
            const float* bp = (const float*)&b4;
            #pragma unroll
            for (int r = 0; r < 4; ++r)
                #pragma unroll
                for (int c = 0; c < 4; ++c)
                    acc[r][c] += ap[r] * bp[c];
        }
        __syncthreads();
    }
    #pragma unroll
    for (int r = 0; r < 4; ++r) {
        int m = m0 + tm*4 + r;
        #pragma unroll
        for (int c = 0; c < 4; ++c) {
            int n = n0 + tn*4 + c;
            if (n >= DIN_ALL) continue;
            float v = acc[r][c];
            if (n < DINNER) {
                Z[(size_t)m*DINNER + n] = v;
            } else if (n < DINNER + CONVD) {
                XBC[(size_t)m*CONVD + (n - DINNER)] = v;
            } else {
                int hh = n - (DINNER + CONVD);
                DT[(size_t)m*NH + hh] = softplusf(v + dtb[hh]);
            }
        }
    }
}

// ----------------------------------------------------------------- scan -----
// Fused depthwise causal conv(4)+SiLU + SSM scan. One block per (e_local,b,h).
// Buffers (XBC, DT) are indexed by e_local (buffer slot); weight arrays by
// e_off + e_local (global expert id). y written IN PLACE into XBC cols
// [h*64, h*64+64); B/C cols 1024..1279 never written.
__global__ void __launch_bounds__(256) scan_kernel(
    float* __restrict__ XBC,          // (ne) x M x 1280  (read raw / write y)
    const float* __restrict__ DT,     // (ne) x M x 16 (post-softplus)
    const float* __restrict__ conv_w, // E x 1280 x 4
    const float* __restrict__ conv_b, // E x 1280
    const float* __restrict__ A_log,  // E x 16
    const float* __restrict__ Dskip,  // E x 16
    int e_off)
{
    const int bx = blockIdx.x;
    const int h  = bx % NH;
    const int b  = (bx / NH) % BATCH;
    const int el = bx / (NH * BATCH);   // buffer slot
    const int eg = e_off + el;          // global expert (weights)
    const int t  = threadIdx.x;

    __shared__ float ring[4][320];
    __shared__ float cv[320];

    const int col1 = (t < 64) ? h*64 + t : 960 + t;          // c = t
    const int col2 = 1216 + t;                                // c = 256+t (t<64)

    float w1[4], w2[4] = {0,0,0,0};
    #pragma unroll
    for (int j = 0; j < 4; ++j) w1[j] = conv_w[((size_t)eg*CONVD + col1)*4 + j];
    float b1 = conv_b[eg*CONVD + col1];
    float b2 = 0.f;
    if (t < 64) {
        #pragma unroll
        for (int j = 0; j < 4; ++j) w2[j] = conv_w[((size_t)eg*CONVD + col2)*4 + j];
        b2 = conv_b[eg*CONVD + col2];
    }
    const float Ah = -expf(A_log[eg*NH + h]);
    const float Dv = Dskip[eg*NH + h];

    const size_t rowbase = ((size_t)el*M_TOK + (size_t)b*L_SEQ) * CONVD;
    const size_t dtbase  = ((size_t)el*M_TOK + (size_t)b*L_SEQ) * NH + h;

    for (int i = t; i < 4*320; i += 256) ((float*)ring)[i] = 0.f;
    __syncthreads();
    {   // row 0 -> ring slot 0
        const float* r0 = XBC + rowbase;
        ring[0][t] = r0[col1];
        if (t < 64) ring[0][256 + t] = r0[col2];
    }
    __syncthreads();

    const int p  = t >> 2;
    const int ns = (t & 3) * 32;
    float hreg[32];
    #pragma unroll
    for (int i = 0; i < 32; ++i) hreg[i] = 0.f;

    for (int l = 0; l < L_SEQ; ++l) {
        const size_t rb = rowbase + (size_t)l * CONVD;
        // issue next-row loads early (hidden under conv+compute)
        float n1 = 0.f, n2 = 0.f;
        if (l + 1 < L_SEQ) {
            const float* rn = XBC + rb + CONVD;
            n1 = rn[col1];
            if (t < 64) n2 = rn[col2];
        }
        // conv + SiLU for this thread's channel(s)
        {
            const int s0 = (l+1)&3, s1 = (l+2)&3, s2 = (l+3)&3, s3 = l&3;
            float o1 = ring[s0][t]*w1[0] + ring[s1][t]*w1[1]
                     + ring[s2][t]*w1[2] + ring[s3][t]*w1[3] + b1;
            cv[t] = siluf(o1);
            if (t < 64) {
                float o2 = ring[s0][256+t]*w2[0] + ring[s1][256+t]*w2[1]
                         + ring[s2][256+t]*w2[2] + ring[s3][256+t]*w2[3] + b2;
                cv[256 + t] = siluf(o2);
            }
        }
        __syncthreads();
        // SSM update
        const float dt = DT[dtbase + (size_t)l * NH];
        const float dA = expf(dt * Ah);
        const float xp = cv[p];
        const float sx = dt * xp;
        float ys = 0.f;
        #pragma unroll
        for (int i = 0; i < 32; ++i) {
            const int n = ns + i;
            hreg[i] = hreg[i]*dA + sx*cv[64 + n];
            ys += hreg[i]*cv[192 + n];
        }
        ys += __shfl_xor(ys, 1);
        ys += __shfl_xor(ys, 2);
        // stash next row into ring (waits the global loads here)
        if (l + 1 < L_SEQ) {
            const int sl = (l+1)&3;
            ring[sl][t] = n1;
            if (t < 64) ring[sl][256 + t] = n2;
        }
        if ((t & 3) == 0)
            XBC[rb + h*64 + p] = ys + xp*Dv;
        __syncthreads();
    }
}

// ------------------------------------------------------- gated RMS norm -----
// ONE expert per call; pointers pre-offset.
__global__ void __launch_bounds__(256) norm_kernel(
    float* __restrict__ Ybuf,          // M rows, stride 1280, in-place
    const float* __restrict__ Z,       // M x 1024
    const float* __restrict__ nw)      // 1024 (expert slice)
{
    const int row = blockIdx.x;        // m
    const int t = threadIdx.x;
    float* y = Ybuf + (size_t)row * CONVD;
    const float* z = Z + (size_t)row * DINNER;

    float4 yv = *(const float4*)(y + t*4);
    float4 zv = *(const float4*)(z + t*4);
    float v[4]; float ss = 0.f;
    #pragma unroll
    for (int j = 0; j < 4; ++j) {
        float zz = ((const float*)&zv)[j];
        float vv = ((const float*)&yv)[j] * siluf(zz);
        v[j] = vv; ss += vv*vv;
    }
    #pragma unroll
    for (int o = 32; o > 0; o >>= 1) ss += __shfl_down(ss, o);
    __shared__ float wsum[4];
    if ((t & 63) == 0) wsum[t >> 6] = ss;
    __syncthreads();
    const float total = wsum[0] + wsum[1] + wsum[2] + wsum[3];
    const float scale = rsqrtf(total / (float)DINNER + 1e-5f);
    float4 ov;
    #pragma unroll
    for (int j = 0; j < 4; ++j) ((float*)&ov)[j] = v[j] * scale * nw[t*4 + j];
    *(float4*)(y + t*4) = ov;
}

// ----------------------------------------- out_proj + weighted combine -----
// out[m][n] (+)= mask[m][e] * ( yn[m][:1024] @ Wo^T )[n]; ONE expert per call.
__global__ void __launch_bounds__(256) gemm_outproj(
    const float* __restrict__ Yn,   // M rows, stride 1280 (expert slice)
    const float* __restrict__ Wo,   // 512 x 1024 (expert slice)
    const float* __restrict__ mask, // M x 4
    float* __restrict__ out,        // M x 512
    int e, int first)
{
    const int m0 = blockIdx.y * 64;
    const int n0 = blockIdx.x * 64;
    const int t  = threadIdx.x;
    __shared__ float As[16][64];
    __shared__ float Bs[16][64];
    const int tm = t >> 4, tn = t & 15;
    const int lr = t >> 2;
    const int lk = (t & 3) * 4;
    float acc[4][4] = {};

    for (int k0 = 0; k0 < DINNER; k0 += 16) {
        float4 av = *(const float4*)(Yn + (size_t)(m0 + lr) * CONVD + k0 + lk);
        float4 bv = *(const float4*)(Wo + (size_t)(n0 + lr) * DINNER + k0 + lk);
        #pragma unroll
        for (int j = 0; j < 4; ++j) {
            As[lk + j][lr] = ((const float*)&av)[j];
            Bs[lk + j][lr] = ((const float*)&bv)[j];
        }
        __syncthreads();
        #pragma unroll
        for (int kk = 0; kk < 16; ++kk) {
            float4 a4 = *(const float4*)&As[kk][tm*4];
            float4 b4 = *(const float4*)&Bs[kk][tn*4];
            const float* ap = (const float*)&a4;
            const float* bp = (const float*)&b4;
            #pragma unroll
            for (int r = 0; r < 4; ++r)
                #pragma unroll
                for (int c = 0; c < 4; ++c)
                    acc[r][c] += ap[r] * bp[c];
        }
        __syncthreads();
    }
    #pragma unroll
    for (int r = 0; r < 4; ++r) {
        int m = m0 + tm*4 + r;
        float w = mask[m*4 + e];
        #pragma unroll
        for (int c = 0; c < 4; ++c) {
            int n = n0 + tn*4 + c;
            size_t o = (size_t)m*DMODEL + n;
            float v = w * acc[r][c];
            out[o] = first ? v : out[o] + v;
        }
    }
}

// ------------------------------------------------------------------ host ----
extern "C" void kernel_launch(void* const* d_in, const int* in_sizes, int n_in,
                              void* d_out, int out_size, void* d_ws, size_t ws_size,
                              hipStream_t stream)
{
    const float* x        = (const float*)d_in[0];
    const float* gate_w   = (const float*)d_in[1];
    const float* gate_b   = (const float*)d_in[2];
    const float* gate_n   = (const float*)d_in[3];
    const float* in_w     = (const float*)d_in[4];
    const float* conv_w   = (const float*)d_in[5];
    const float* conv_b   = (const float*)d_in[6];
    const float* dt_bias  = (const float*)d_in[7];
    const float* A_log    = (const float*)d_in[8];
    const float* Dskip    = (const float*)d_in[9];
    const float* norm_w   = (const float*)d_in[10];
    const float* out_w    = (const float*)d_in[11];
    float* out = (float*)d_out;

    const size_t XBC_E = (size_t)M_TOK * CONVD;   // floats per expert
    const size_t Z_E   = (size_t)M_TOK * DINNER;
    const size_t DT_E  = (size_t)M_TOK * NH;
    const size_t NEED_BIG =
        (XBC_E*NEXP + Z_E*NEXP + DT_E*NEXP + (size_t)M_TOK*4) * sizeof(float);
    const bool big = ws_size >= NEED_BIG;
    const int NE = big ? NEXP : 1;   // experts resident in workspace

    float* XBC   = (float*)d_ws;
    float* Zb    = XBC + XBC_E * NE;
    float* DTb   = Zb  + Z_E * NE;
    float* maskb = DTb + DT_E * NE;

    gate_kernel<<<M_TOK, 64, 0, stream>>>(x, gate_w, gate_b, gate_n, maskb);

    if (big) {
        for (int e = 0; e < NEXP; ++e)
            gemm_inproj<<<dim3(37, 125), 256, 0, stream>>>(
                x, in_w + (size_t)e*DIN_ALL*DMODEL, dt_bias + e*NH,
                XBC + e*XBC_E, Zb + e*Z_E, DTb + e*DT_E);
        scan_kernel<<<NEXP*BATCH*NH, 256, 0, stream>>>(
            XBC, DTb, conv_w, conv_b, A_log, Dskip, 0);
        for (int e = 0; e < NEXP; ++e)
            norm_kernel<<<M_TOK, 256, 0, stream>>>(
                XBC + e*XBC_E, Zb + e*Z_E, norm_w + (size_t)e*DINNER);
        for (int e = 0; e < NEXP; ++e)
            gemm_outproj<<<dim3(8, 125), 256, 0, stream>>>(
                XBC + e*XBC_E, out_w + (size_t)e*DMODEL*DINNER,
                maskb, out, e, e == 0 ? 1 : 0);
    } else {
        for (int e = 0; e < NEXP; ++e) {
            gemm_inproj<<<dim3(37, 125), 256, 0, stream>>>(
                x, in_w + (size_t)e*DIN_ALL*DMODEL, dt_bias + e*NH,
                XBC, Zb, DTb);
            scan_kernel<<<BATCH*NH, 256, 0, stream>>>(
                XBC, DTb, conv_w, conv_b, A_log, Dskip, e);
            norm_kernel<<<M_TOK, 256, 0, stream>>>(
                XBC, Zb, norm_w + (size_t)e*DINNER);
            gemm_outproj<<<dim3(8, 125), 256, 0, stream>>>(
                XBC, out_w + (size_t)e*DMODEL*DINNER,
                maskb, out, e, e == 0 ? 1 : 0);
        }
    }
}

// Round 3
// 4022.808 us; speedup vs baseline: 2.2424x; 2.2424x over previous
//
#include <hip/hip_runtime.h>
#include <hip/hip_bf16.h>

#define M_TOK   8000
#define L_SEQ   2000
#define BATCH   4
#define NEXP    4
#define NH      16
#define HD      64
#define DSTATE  128
#define DMODEL  512
#define DINNER  1024
#define CONVD   1280
#define DIN_ALL 2320   // 1024 z + 1280 xBC + 16 dt
#define CS      250    // chunk size (steps)
#define NCH     8      // chunks per sequence (CS*NCH == L_SEQ)

__device__ __forceinline__ float siluf(float v) {
    return v / (1.f + __expf(-v));
}
__device__ __forceinline__ float softplusf(float v) {
    return v > 20.f ? v : log1pf(expf(v));
}

// ---------------------------------------------------------------- gating ----
__global__ void __launch_bounds__(64) gate_kernel(
    const float* __restrict__ X,    // M x 512
    const float* __restrict__ GW,   // 4 x 512
    const float* __restrict__ GB,   // 4
    const float* __restrict__ GN,   // M x 4
    float* __restrict__ mask)       // M x 4
{
    const int m = blockIdx.x;
    const int t = threadIdx.x;
    const float* x = X + (size_t)m * DMODEL;
    float s0 = 0.f, s1 = 0.f, s2 = 0.f, s3 = 0.f;
    for (int k = t; k < DMODEL; k += 64) {
        float xv = x[k];
        s0 += xv * GW[k];
        s1 += xv * GW[512 + k];
        s2 += xv * GW[1024 + k];
        s3 += xv * GW[1536 + k];
    }
    #pragma unroll
    for (int o = 32; o > 0; o >>= 1) {
        s0 += __shfl_down(s0, o);
        s1 += __shfl_down(s1, o);
        s2 += __shfl_down(s2, o);
        s3 += __shfl_down(s3, o);
    }
    if (t == 0) {
        float lg[4] = { s0 + GB[0] + GN[m*4+0]*0.01f,
                        s1 + GB[1] + GN[m*4+1]*0.01f,
                        s2 + GB[2] + GN[m*4+2]*0.01f,
                        s3 + GB[3] + GN[m*4+3]*0.01f };
        float mx = fmaxf(fmaxf(lg[0], lg[1]), fmaxf(lg[2], lg[3]));
        float p[4]; float sum = 0.f;
        #pragma unroll
        for (int e = 0; e < 4; ++e) { p[e] = expf(lg[e] - mx); sum += p[e]; }
        #pragma unroll
        for (int e = 0; e < 4; ++e) p[e] /= sum;
        int i0 = 0;
        #pragma unroll
        for (int e = 1; e < 4; ++e) if (p[e] > p[i0]) i0 = e;
        int i1 = -1;
        #pragma unroll
        for (int e = 0; e < 4; ++e) {
            if (e == i0) continue;
            if (i1 < 0 || p[e] > p[i1]) i1 = e;
        }
        float s2v = p[i0] + p[i1];
        #pragma unroll
        for (int e = 0; e < 4; ++e)
            mask[m*4 + e] = (e == i0 || e == i1) ? p[e] / s2v : 0.f;
    }
}

// --------------------------------------------------- in_proj (xBC+dt part) --
// cols 1024..2320 of in_proj: xBC (1280) + dt (16). ONE expert per call.
__global__ void __launch_bounds__(256) gemm_xbcdt(
    const float* __restrict__ X,
    const float* __restrict__ Wb,      // expert base: 2320 x 512
    const float* __restrict__ dtb,     // 16
    float* __restrict__ XBC,           // M x 1280
    float* __restrict__ DT)            // M x 16
{
    const int m0 = blockIdx.y * 64;
    const int n0 = blockIdx.x * 64;    // local col in [0,1296)
    const int t  = threadIdx.x;
    __shared__ float As[16][64];
    __shared__ float Bs[16][64];
    const int tm = t >> 4, tn = t & 15;
    const int lr = t >> 2;
    const int lk = (t & 3) * 4;
    float acc[4][4] = {};

    for (int k0 = 0; k0 < DMODEL; k0 += 16) {
        float4 av = *(const float4*)(X + (size_t)(m0 + lr) * DMODEL + k0 + lk);
        int nloc = n0 + lr;
        float4 bv = make_float4(0.f, 0.f, 0.f, 0.f);
        if (nloc < 1296)
            bv = *(const float4*)(Wb + (size_t)(1024 + nloc) * DMODEL + k0 + lk);
        #pragma unroll
        for (int j = 0; j < 4; ++j) {
            As[lk + j][lr] = ((const float*)&av)[j];
            Bs[lk + j][lr] = ((const float*)&bv)[j];
        }
        __syncthreads();
        #pragma unroll
        for (int kk = 0; kk < 16; ++kk) {
            float4 a4 = *(const float4*)&As[kk][tm*4];
            float4 b4 = *(const float4*)&Bs[kk][tn*4];
            const float* ap = (const float*)&a4;
            const float* bp = (const float*)&b4;
            #pragma unroll
            for (int r = 0; r < 4; ++r)
                #pragma unroll
                for (int c = 0; c < 4; ++c)
                    acc[r][c] += ap[r] * bp[c];
        }
        __syncthreads();
    }
    #pragma unroll
    for (int r = 0; r < 4; ++r) {
        int m = m0 + tm*4 + r;
        #pragma unroll
        for (int c = 0; c < 4; ++c) {
            int nloc = n0 + tn*4 + c;
            if (nloc >= 1296) continue;
            float v = acc[r][c];
            if (nloc < CONVD) XBC[(size_t)m*CONVD + nloc] = v;
            else DT[(size_t)m*NH + (nloc - CONVD)] = softplusf(v + dtb[nloc - CONVD]);
        }
    }
}

// ------------------------------------------------------- boundary stash -----
// Copies raw rows g*CS-3..g*CS-1 (zeros if <0) to a side buffer so chunked
// scan blocks never read rows another chunk may have overwritten with y.
__global__ void __launch_bounds__(256) stash_kernel(
    const float* __restrict__ XBC,   // M x 1280
    float* __restrict__ bound)       // B x NCH x 3 x 1280
{
    const int bk = blockIdx.x;       // b*NCH + g
    const int g = bk % NCH, b = bk / NCH;
    const int t = threadIdx.x;
    #pragma unroll
    for (int k = 0; k < 3; ++k) {
        int row = g*CS - 3 + k;
        float* dst = bound + ((size_t)bk*3 + k)*CONVD;
        if (row < 0) {
            for (int c = t; c < CONVD; c += 256) dst[c] = 0.f;
        } else {
            const float* src = XBC + ((size_t)b*L_SEQ + row)*CONVD;
            for (int c = t; c < CONVD; c += 256) dst[c] = src[c];
        }
    }
}

// ------------------------------------------------- pass 1: chunked scan -----
// Fused conv(4)+SiLU + local SSM scan (zero initial state per chunk).
// One block per (g, b, h). Writes y_local in place into XBC x-cols, c_l to
// cbuf, conv'd C rows to Cconv (h==0 blocks), final local state to Hend.
__global__ void __launch_bounds__(256) scan_chunk(
    float* __restrict__ XBC,          // M x 1280
    const float* __restrict__ DT,     // M x 16
    const float* __restrict__ bound,  // B x NCH x 3 x 1280
    float* __restrict__ Cconv,        // B x L x 128
    float* __restrict__ Hend,         // (bh*NCH+g) x 64 x 128
    float* __restrict__ cbuf,         // bh x L
    const float* __restrict__ conv_w, // E x 1280 x 4
    const float* __restrict__ conv_b, // E x 1280
    const float* __restrict__ A_log,  // E x 16
    const float* __restrict__ Dskip,  // E x 16
    int eg)
{
    const int bx = blockIdx.x;
    const int h  = bx % NH;
    const int b  = (bx / NH) % BATCH;
    const int g  = bx / (NH * BATCH);
    const int t  = threadIdx.x;
    const int bh = b * NH + h;

    __shared__ float ring[4][320];
    __shared__ float cv[320];

    const int col1 = (t < 64) ? h*64 + t : 960 + t;
    const int col2 = 1216 + t;

    float w1[4], w2[4] = {0,0,0,0};
    #pragma unroll
    for (int j = 0; j < 4; ++j) w1[j] = conv_w[((size_t)eg*CONVD + col1)*4 + j];
    float b1 = conv_b[eg*CONVD + col1];
    float b2 = 0.f;
    if (t < 64) {
        #pragma unroll
        for (int j = 0; j < 4; ++j) w2[j] = conv_w[((size_t)eg*CONVD + col2)*4 + j];
        b2 = conv_b[eg*CONVD + col2];
    }
    const float Ah = -expf(A_log[eg*NH + h]);
    const float Dv = Dskip[eg*NH + h];

    const int l0 = g * CS, lend = l0 + CS;
    const size_t rowbase = (size_t)b * L_SEQ * CONVD;
    const size_t dtbase  = ((size_t)b * L_SEQ) * NH + h;

    {   // ring init: rows l0-3..l0-1 from bound, row l0 from XBC
        const float* bb = bound + ((size_t)(b*NCH + g)*3)*CONVD;
        #pragma unroll
        for (int k = 0; k < 3; ++k) {
            const int sl = (l0 - 3 + k) & 3;
            ring[sl][t] = bb[k*CONVD + col1];
            if (t < 64) ring[sl][256 + t] = bb[k*CONVD + col2];
        }
        const float* r0 = XBC + rowbase + (size_t)l0 * CONVD;
        ring[l0 & 3][t] = r0[col1];
        if (t < 64) ring[l0 & 3][256 + t] = r0[col2];
    }
    __syncthreads();

    const int p   = t >> 2;
    const int grp = t & 3;
    const int ns  = grp * 32;
    const int rot = grp * 8;
    float hreg[32];
    #pragma unroll
    for (int i = 0; i < 32; ++i) hreg[i] = 0.f;
    float c = 1.f;
    float dt_cur = DT[dtbase + (size_t)l0 * NH];

    for (int l = l0; l < lend; ++l) {
        const size_t rb = rowbase + (size_t)l * CONVD;
        float n1 = 0.f, n2 = 0.f, dtn = 0.f;
        if (l + 1 < lend) {
            const float* rn = XBC + rb + CONVD;
            n1 = rn[col1];
            if (t < 64) n2 = rn[col2];
            dtn = DT[dtbase + (size_t)(l+1) * NH];
        }
        {   // conv + SiLU
            const int s0 = (l+1)&3, s1 = (l+2)&3, s2_ = (l+3)&3, s3 = l&3;
            float o1 = ring[s0][t]*w1[0] + ring[s1][t]*w1[1]
                     + ring[s2_][t]*w1[2] + ring[s3][t]*w1[3] + b1;
            cv[t] = siluf(o1);
            if (t < 64) {
                float o2 = ring[s0][256+t]*w2[0] + ring[s1][256+t]*w2[1]
                         + ring[s2_][256+t]*w2[2] + ring[s3][256+t]*w2[3] + b2;
                cv[256 + t] = siluf(o2);
            }
        }
        __syncthreads();
        if (h == 0 && t < 128)
            Cconv[((size_t)b*L_SEQ + l)*128 + t] = cv[192 + t];
        const float dA = expf(dt_cur * Ah);
        c *= dA;
        if (t == 0) cbuf[(size_t)bh*L_SEQ + l] = c;
        const float xp = cv[p];
        const float sx = dt_cur * xp;
        float ys = 0.f;
        #pragma unroll
        for (int i = 0; i < 32; ++i) {
            const int n = ns + ((i + rot) & 31);    // rotated: bank-conflict-free
            hreg[i] = hreg[i]*dA + sx*cv[64 + n];
            ys += hreg[i]*cv[192 + n];
        }
        ys += __shfl_xor(ys, 1);
        ys += __shfl_xor(ys, 2);
        if (l + 1 < lend) {
            const int sl = (l+1)&3;
            ring[sl][t] = n1;
            if (t < 64) ring[sl][256 + t] = n2;
        }
        if (grp == 0)
            XBC[rb + h*64 + p] = ys + xp*Dv;
        dt_cur = dtn;
        __syncthreads();
    }
    // store final local state (unrotated layout)
    float* He = Hend + ((size_t)(bh*NCH + g)*64 + p)*128;
    #pragma unroll
    for (int i = 0; i < 32; ++i) {
        const int n = ns + ((i + rot) & 31);
        He[n] = hreg[i];
    }
}

// --------------------------------------- pass 2: chunk-state propagation ----
// Sequential over chunks (tiny). Rewrites Hend[g-1] with h_start[g].
__global__ void __launch_bounds__(256) prop_kernel(
    float* __restrict__ Hend,         // (bh*NCH+g) x 64 x 128
    const float* __restrict__ cbuf)   // bh x L
{
    const int bh = blockIdx.x;
    const int t  = threadIdx.x;
    const int p  = t >> 2;
    const int ns = (t & 3) * 32;
    float hs[32];
    #pragma unroll
    for (int j = 0; j < 32; ++j) hs[j] = 0.f;
    for (int g = 1; g < NCH; ++g) {
        const float ce = cbuf[(size_t)bh*L_SEQ + g*CS - 1];
        float* He = Hend + ((size_t)(bh*NCH + g-1)*64 + p)*128 + ns;
        #pragma unroll
        for (int j = 0; j < 32; ++j) {
            float he = He[j];
            hs[j] = ce*hs[j] + he;
            He[j] = hs[j];        // slot g-1 now holds h_start[g]
        }
    }
}

// --------------------------------------------- pass 3: y correction ---------
// y(l) += c_l * (C_l . h_start[g]);  chunk 0 needs none.
__global__ void __launch_bounds__(256) correct_kernel(
    float* __restrict__ XBC,
    const float* __restrict__ Cconv,  // B x L x 128
    const float* __restrict__ Hend,   // slot g-1 holds h_start[g]
    const float* __restrict__ cbuf)
{
    const int bx = blockIdx.x;
    const int g  = bx / (NH * BATCH);
    if (g == 0) return;
    const int h  = bx % NH;
    const int b  = (bx / NH) % BATCH;
    const int t  = threadIdx.x;
    const int bh = b * NH + h;
    const int p   = t >> 2;
    const int grp = t & 3;
    const int ns  = grp * 32;
    const int rot = grp * 8;

    __shared__ float cvC[128];

    const float* He = Hend + ((size_t)(bh*NCH + g-1)*64 + p)*128;
    float h0[32];
    #pragma unroll
    for (int i = 0; i < 32; ++i) h0[i] = He[ns + ((i + rot) & 31)];

    const int l0 = g * CS, lend = l0 + CS;
    const size_t rowbase = (size_t)b * L_SEQ * CONVD;
    for (int l = l0; l < lend; ++l) {
        if (t < 128) cvC[t] = Cconv[((size_t)b*L_SEQ + l)*128 + t];
        __syncthreads();
        const float cl = cbuf[(size_t)bh*L_SEQ + l];
        float s = 0.f;
        #pragma unroll
        for (int i = 0; i < 32; ++i)
            s += h0[i] * cvC[ns + ((i + rot) & 31)];
        s += __shfl_xor(s, 1);
        s += __shfl_xor(s, 2);
        if (grp == 0)
            XBC[rowbase + (size_t)l*CONVD + h*64 + p] += cl * s;
        __syncthreads();
    }
}

// ------------------------------------------------- in_proj (z part), tiled --
// z rows [m_off, m_off+2000): Ztile = X[m_off..] @ Wz^T (1024 x 512)
__global__ void __launch_bounds__(256) gemm_z(
    const float* __restrict__ X,
    const float* __restrict__ Wz,      // expert base (z rows = first 1024)
    float* __restrict__ Z,             // 2000 x 1024 tile
    int m_off)
{
    const int m0 = blockIdx.y * 64;    // local row in [0,2048)
    const int n0 = blockIdx.x * 64;
    const int t  = threadIdx.x;
    __shared__ float As[16][64];
    __shared__ float Bs[16][64];
    const int tm = t >> 4, tn = t & 15;
    const int lr = t >> 2;
    const int lk = (t & 3) * 4;
    float acc[4][4] = {};

    for (int k0 = 0; k0 < DMODEL; k0 += 16) {
        int mloc = m0 + lr;
        size_t arow = (size_t)m_off + (mloc < 2000 ? mloc : 0);
        float4 av = *(const float4*)(X + arow * DMODEL + k0 + lk);
        float4 bv = *(const float4*)(Wz + (size_t)(n0 + lr) * DMODEL + k0 + lk);
        #pragma unroll
        for (int j = 0; j < 4; ++j) {
            As[lk + j][lr] = ((const float*)&av)[j];
            Bs[lk + j][lr] = ((const float*)&bv)[j];
        }
        __syncthreads();
        #pragma unroll
        for (int kk = 0; kk < 16; ++kk) {
            float4 a4 = *(const float4*)&As[kk][tm*4];
            float4 b4 = *(const float4*)&Bs[kk][tn*4];
            const float* ap = (const float*)&a4;
            const float* bp = (const float*)&b4;
            #pragma unroll
            for (int r = 0; r < 4; ++r)
                #pragma unroll
                for (int c = 0; c < 4; ++c)
                    acc[r][c] += ap[r] * bp[c];
        }
        __syncthreads();
    }
    #pragma unroll
    for (int r = 0; r < 4; ++r) {
        int m = m0 + tm*4 + r;
        if (m >= 2000) continue;
        #pragma unroll
        for (int c = 0; c < 4; ++c) {
            int n = n0 + tn*4 + c;
            Z[(size_t)m*DINNER + n] = acc[r][c];
        }
    }
}

// ------------------------------------------------------- gated RMS norm -----
__global__ void __launch_bounds__(256) norm_kernel(
    float* __restrict__ Ybuf,          // rows, stride 1280, in-place
    const float* __restrict__ Z,       // rows x 1024
    const float* __restrict__ nw)      // 1024
{
    const int row = blockIdx.x;
    const int t = threadIdx.x;
    float* y = Ybuf + (size_t)row * CONVD;
    const float* z = Z + (size_t)row * DINNER;

    float4 yv = *(const float4*)(y + t*4);
    float4 zv = *(const float4*)(z + t*4);
    float v[4]; float ss = 0.f;
    #pragma unroll
    for (int j = 0; j < 4; ++j) {
        float zz = ((const float*)&zv)[j];
        float vv = ((const float*)&yv)[j] * siluf(zz);
        v[j] = vv; ss += vv*vv;
    }
    #pragma unroll
    for (int o = 32; o > 0; o >>= 1) ss += __shfl_down(ss, o);
    __shared__ float wsum[4];
    if ((t & 63) == 0) wsum[t >> 6] = ss;
    __syncthreads();
    const float total = wsum[0] + wsum[1] + wsum[2] + wsum[3];
    const float scale = rsqrtf(total / (float)DINNER + 1e-5f);
    float4 ov;
    #pragma unroll
    for (int j = 0; j < 4; ++j) ((float*)&ov)[j] = v[j] * scale * nw[t*4 + j];
    *(float4*)(y + t*4) = ov;
}

// ----------------------------------------- out_proj + weighted combine -----
__global__ void __launch_bounds__(256) gemm_outproj(
    const float* __restrict__ Yn,   // M rows, stride 1280
    const float* __restrict__ Wo,   // 512 x 1024
    const float* __restrict__ mask, // M x 4
    float* __restrict__ out,        // M x 512
    int e, int first)
{
    const int m0 = blockIdx.y * 64;
    const int n0 = blockIdx.x * 64;
    const int t  = threadIdx.x;
    __shared__ float As[16][64];
    __shared__ float Bs[16][64];
    const int tm = t >> 4, tn = t & 15;
    const int lr = t >> 2;
    const int lk = (t & 3) * 4;
    float acc[4][4] = {};

    for (int k0 = 0; k0 < DINNER; k0 += 16) {
        float4 av = *(const float4*)(Yn + (size_t)(m0 + lr) * CONVD + k0 + lk);
        float4 bv = *(const float4*)(Wo + (size_t)(n0 + lr) * DINNER + k0 + lk);
        #pragma unroll
        for (int j = 0; j < 4; ++j) {
            As[lk + j][lr] = ((const float*)&av)[j];
            Bs[lk + j][lr] = ((const float*)&bv)[j];
        }
        __syncthreads();
        #pragma unroll
        for (int kk = 0; kk < 16; ++kk) {
            float4 a4 = *(const float4*)&As[kk][tm*4];
            float4 b4 = *(const float4*)&Bs[kk][tn*4];
            const float* ap = (const float*)&a4;
            const float* bp = (const float*)&b4;
            #pragma unroll
            for (int r = 0; r < 4; ++r)
                #pragma unroll
                for (int c = 0; c < 4; ++c)
                    acc[r][c] += ap[r] * bp[c];
        }
        __syncthreads();
    }
    #pragma unroll
    for (int r = 0; r < 4; ++r) {
        int m = m0 + tm*4 + r;
        float w = mask[m*4 + e];
        #pragma unroll
        for (int c = 0; c < 4; ++c) {
            int n = n0 + tn*4 + c;
            size_t o = (size_t)m*DMODEL + n;
            float v = w * acc[r][c];
            out[o] = first ? v : out[o] + v;
        }
    }
}

// ------------------------------------------------------------------ host ----
extern "C" void kernel_launch(void* const* d_in, const int* in_sizes, int n_in,
                              void* d_out, int out_size, void* d_ws, size_t ws_size,
                              hipStream_t stream)
{
    const float* x        = (const float*)d_in[0];
    const float* gate_w   = (const float*)d_in[1];
    const float* gate_b   = (const float*)d_in[2];
    const float* gate_n   = (const float*)d_in[3];
    const float* in_w     = (const float*)d_in[4];
    const float* conv_w   = (const float*)d_in[5];
    const float* conv_b   = (const float*)d_in[6];
    const float* dt_bias  = (const float*)d_in[7];
    const float* A_log    = (const float*)d_in[8];
    const float* Dskip    = (const float*)d_in[9];
    const float* norm_w   = (const float*)d_in[10];
    const float* out_w    = (const float*)d_in[11];
    float* out = (float*)d_out;

    // workspace layout (floats); total ~63.5 MB (known-safe: >=74.4 MB exists)
    float* XBC   = (float*)d_ws;                    // 10,240,000
    float* DTb   = XBC  + (size_t)10240000;         //    128,000
    float* Hend  = DTb  + (size_t)128000;           //  4,194,304
    float* cbuf  = Hend + (size_t)4194304;          //    128,000
    float* Cconv = cbuf + (size_t)128000;           //  1,024,000
    float* bound = Cconv+ (size_t)1024000;          //    122,880
    float* maskb = bound+ (size_t)122880;           //     32,000
    float* Ztile = Hend;                            //  2,048,000 (alias, dead Hend)

    gate_kernel<<<M_TOK, 64, 0, stream>>>(x, gate_w, gate_b, gate_n, maskb);

    for (int e = 0; e < NEXP; ++e) {
        const float* Wb = in_w + (size_t)e * DIN_ALL * DMODEL;
        gemm_xbcdt<<<dim3(21, 125), 256, 0, stream>>>(
            x, Wb, dt_bias + e*NH, XBC, DTb);
        stash_kernel<<<BATCH*NCH, 256, 0, stream>>>(XBC, bound);
        scan_chunk<<<NCH*BATCH*NH, 256, 0, stream>>>(
            XBC, DTb, bound, Cconv, Hend, cbuf,
            conv_w, conv_b, A_log, Dskip, e);
        prop_kernel<<<BATCH*NH, 256, 0, stream>>>(Hend, cbuf);
        correct_kernel<<<NCH*BATCH*NH, 256, 0, stream>>>(XBC, Cconv, Hend, cbuf);
        for (int mt = 0; mt < 4; ++mt) {
            gemm_z<<<dim3(16, 32), 256, 0, stream>>>(x, Wb, Ztile, mt*2000);
            norm_kernel<<<2000, 256, 0, stream>>>(
                XBC + (size_t)mt*2000*CONVD, Ztile, norm_w + (size_t)e*DINNER);
        }
        gemm_outproj<<<dim3(8, 125), 256, 0, stream>>>(
            XBC, out_w + (size_t)e*DMODEL*DINNER, maskb, out, e, e == 0 ? 1 : 0);
    }
}

// Round 4
// 2806.467 us; speedup vs baseline: 3.2143x; 1.4334x over previous
//
#include <hip/hip_runtime.h>
#include <hip/hip_bf16.h>

#define M_TOK   8000
#define L_SEQ   2000
#define BATCH   4
#define NEXP    4
#define NH      16
#define HD      64
#define DSTATE  128
#define DMODEL  512
#define DINNER  1024
#define CONVD   1280
#define DIN_ALL 2320   // 1024 z + 1280 xBC + 16 dt
#define CS      125    // chunk size (steps)
#define NCH     16     // chunks per sequence (CS*NCH == L_SEQ)

typedef __attribute__((ext_vector_type(8))) short short8;
typedef __attribute__((ext_vector_type(4))) float f32x4;

__device__ __forceinline__ float siluf(float v) {
    return v / (1.f + __expf(-v));
}
__device__ __forceinline__ float softplusf(float v) {
    return v > 20.f ? v : log1pf(expf(v));
}
__device__ __forceinline__ unsigned short f2bf(float f) {
    union { float f; unsigned u; } x; x.f = f;
    return (unsigned short)((x.u + 0x7fffu + ((x.u >> 16) & 1u)) >> 16);
}

// ---------------------------------------------------------------- gating ----
__global__ void __launch_bounds__(64) gate_kernel(
    const float* __restrict__ X, const float* __restrict__ GW,
    const float* __restrict__ GB, const float* __restrict__ GN,
    float* __restrict__ mask)
{
    const int m = blockIdx.x;
    const int t = threadIdx.x;
    const float* x = X + (size_t)m * DMODEL;
    float s0 = 0.f, s1 = 0.f, s2 = 0.f, s3 = 0.f;
    for (int k = t; k < DMODEL; k += 64) {
        float xv = x[k];
        s0 += xv * GW[k];
        s1 += xv * GW[512 + k];
        s2 += xv * GW[1024 + k];
        s3 += xv * GW[1536 + k];
    }
    #pragma unroll
    for (int o = 32; o > 0; o >>= 1) {
        s0 += __shfl_down(s0, o);
        s1 += __shfl_down(s1, o);
        s2 += __shfl_down(s2, o);
        s3 += __shfl_down(s3, o);
    }
    if (t == 0) {
        float lg[4] = { s0 + GB[0] + GN[m*4+0]*0.01f,
                        s1 + GB[1] + GN[m*4+1]*0.01f,
                        s2 + GB[2] + GN[m*4+2]*0.01f,
                        s3 + GB[3] + GN[m*4+3]*0.01f };
        float mx = fmaxf(fmaxf(lg[0], lg[1]), fmaxf(lg[2], lg[3]));
        float p[4]; float sum = 0.f;
        #pragma unroll
        for (int e = 0; e < 4; ++e) { p[e] = expf(lg[e] - mx); sum += p[e]; }
        #pragma unroll
        for (int e = 0; e < 4; ++e) p[e] /= sum;
        int i0 = 0;
        #pragma unroll
        for (int e = 1; e < 4; ++e) if (p[e] > p[i0]) i0 = e;
        int i1 = -1;
        #pragma unroll
        for (int e = 0; e < 4; ++e) {
            if (e == i0) continue;
            if (i1 < 0 || p[e] > p[i1]) i1 = e;
        }
        float s2v = p[i0] + p[i1];
        #pragma unroll
        for (int e = 0; e < 4; ++e)
            mask[m*4 + e] = (e == i0 || e == i1) ? p[e] / s2v : 0.f;
    }
}

// --------------------------------------------------------- bf16 MFMA GEMM ---
// OUT[M x N] = A(f32, M x K, stride lda) @ B(f32, N x K row-major)^T
// 128x128 tile, 4 waves, mfma_f32_16x16x32_bf16, f32->bf16 convert in staging.
// MODE 0: OUT=XBC (stride 1280). MODE 1: OUT=Ztile (stride 1024).
// MODE 2: out[m*512+n] (+)= mask[m*4+e] * acc.
template<int MODE>
__global__ void __launch_bounds__(256) gemm_bf16(
    const float* __restrict__ A, int lda, int Mrows,
    const float* __restrict__ B, int K,
    float* __restrict__ OUT,
    const float* __restrict__ mask, int e, int first)
{
    __shared__ unsigned short As[128][40];
    __shared__ unsigned short Bs[128][40];
    const int t  = threadIdx.x;
    const int m0 = blockIdx.y * 128;
    const int n0 = blockIdx.x * 128;
    const int w  = t >> 6, l = t & 63;
    const int wm = (w >> 1) * 64, wn = (w & 1) * 64;
    const int srow = t >> 1;
    const int scol = (t & 1) * 16;

    f32x4 acc[4][4];
    #pragma unroll
    for (int i = 0; i < 4; ++i)
        #pragma unroll
        for (int j = 0; j < 4; ++j) {
            acc[i][j][0] = 0.f; acc[i][j][1] = 0.f;
            acc[i][j][2] = 0.f; acc[i][j][3] = 0.f;
        }

    int arow = m0 + srow; if (arow >= Mrows) arow = Mrows - 1;
    const float* Aptr = A + (size_t)arow * lda + scol;
    const float* Bptr = B + (size_t)(n0 + srow) * K + scol;

    for (int k0 = 0; k0 < K; k0 += 32) {
        float4 a0 = *(const float4*)(Aptr + k0);
        float4 a1 = *(const float4*)(Aptr + k0 + 4);
        float4 a2 = *(const float4*)(Aptr + k0 + 8);
        float4 a3 = *(const float4*)(Aptr + k0 + 12);
        float4 b0 = *(const float4*)(Bptr + k0);
        float4 b1 = *(const float4*)(Bptr + k0 + 4);
        float4 b2 = *(const float4*)(Bptr + k0 + 8);
        float4 b3 = *(const float4*)(Bptr + k0 + 12);
        short8 pa, pa2, pb, pb2;
        pa[0]=f2bf(a0.x); pa[1]=f2bf(a0.y); pa[2]=f2bf(a0.z); pa[3]=f2bf(a0.w);
        pa[4]=f2bf(a1.x); pa[5]=f2bf(a1.y); pa[6]=f2bf(a1.z); pa[7]=f2bf(a1.w);
        pa2[0]=f2bf(a2.x); pa2[1]=f2bf(a2.y); pa2[2]=f2bf(a2.z); pa2[3]=f2bf(a2.w);
        pa2[4]=f2bf(a3.x); pa2[5]=f2bf(a3.y); pa2[6]=f2bf(a3.z); pa2[7]=f2bf(a3.w);
        pb[0]=f2bf(b0.x); pb[1]=f2bf(b0.y); pb[2]=f2bf(b0.z); pb[3]=f2bf(b0.w);
        pb[4]=f2bf(b1.x); pb[5]=f2bf(b1.y); pb[6]=f2bf(b1.z); pb[7]=f2bf(b1.w);
        pb2[0]=f2bf(b2.x); pb2[1]=f2bf(b2.y); pb2[2]=f2bf(b2.z); pb2[3]=f2bf(b2.w);
        pb2[4]=f2bf(b3.x); pb2[5]=f2bf(b3.y); pb2[6]=f2bf(b3.z); pb2[7]=f2bf(b3.w);
        *(short8*)&As[srow][scol]     = pa;
        *(short8*)&As[srow][scol + 8] = pa2;
        *(short8*)&Bs[srow][scol]     = pb;
        *(short8*)&Bs[srow][scol + 8] = pb2;
        __syncthreads();

        short8 af[4], bfr[4];
        const int ko = (l >> 4) * 8;
        #pragma unroll
        for (int i = 0; i < 4; ++i) {
            af[i]  = *(const short8*)&As[wm + i*16 + (l & 15)][ko];
            bfr[i] = *(const short8*)&Bs[wn + i*16 + (l & 15)][ko];
        }
        #pragma unroll
        for (int i = 0; i < 4; ++i)
            #pragma unroll
            for (int j = 0; j < 4; ++j)
                acc[i][j] = __builtin_amdgcn_mfma_f32_16x16x32_bf16(
                    af[i], bfr[j], acc[i][j], 0, 0, 0);
        __syncthreads();
    }

    #pragma unroll
    for (int i = 0; i < 4; ++i) {
        #pragma unroll
        for (int r = 0; r < 4; ++r) {
            const int m = m0 + wm + i*16 + (l >> 4)*4 + r;
            if (m >= Mrows) continue;
            float wgt = 0.f;
            if (MODE == 2) wgt = mask[m*4 + e];
            #pragma unroll
            for (int j = 0; j < 4; ++j) {
                const int n = n0 + wn + j*16 + (l & 15);
                const float v = acc[i][j][r];
                if (MODE == 0) {
                    OUT[(size_t)m*CONVD + n] = v;
                } else if (MODE == 1) {
                    OUT[(size_t)m*DINNER + n] = v;
                } else {
                    const size_t o = (size_t)m*DMODEL + n;
                    const float xv = wgt * v;
                    OUT[o] = first ? xv : OUT[o] + xv;
                }
            }
        }
    }
}

// ------------------------------------------------------------- dt GEMV f32 --
// DT[m][h] = softplus(dot(X[m], W_dt[h]) + dtb[h]); f32 (exp-path sensitive).
__global__ void __launch_bounds__(256) dt_kernel(
    const float* __restrict__ X,
    const float* __restrict__ Wd,    // 16 x 512 (dt rows of in_proj)
    const float* __restrict__ dtb,   // 16
    float* __restrict__ DT)          // M x 16
{
    const int m = blockIdx.x;
    const int t = threadIdx.x;
    __shared__ float xs[512];
    xs[t] = X[(size_t)m*DMODEL + t];
    xs[t + 256] = X[(size_t)m*DMODEL + 256 + t];
    __syncthreads();
    const int w = t >> 6, l = t & 63;
    #pragma unroll
    for (int q = 0; q < 4; ++q) {
        const int hh = w*4 + q;
        const float* wr = Wd + (size_t)hh * DMODEL;
        float s = 0.f;
        for (int k = l; k < DMODEL; k += 64) s += xs[k] * wr[k];
        #pragma unroll
        for (int o = 32; o > 0; o >>= 1) s += __shfl_xor(s, o);
        if (l == 0) DT[(size_t)m*NH + hh] = softplusf(s + dtb[hh]);
    }
}

// ------------------------------------------------------- boundary stash -----
__global__ void __launch_bounds__(256) stash_kernel(
    const float* __restrict__ XBC, float* __restrict__ bound)
{
    const int bk = blockIdx.x;       // b*NCH + g
    const int g = bk % NCH, b = bk / NCH;
    const int t = threadIdx.x;
    #pragma unroll
    for (int k = 0; k < 3; ++k) {
        int row = g*CS - 3 + k;
        float* dst = bound + ((size_t)bk*3 + k)*CONVD;
        if (row < 0) {
            for (int c = t; c < CONVD; c += 256) dst[c] = 0.f;
        } else {
            const float* src = XBC + ((size_t)b*L_SEQ + row)*CONVD;
            for (int c = t; c < CONVD; c += 256) dst[c] = src[c];
        }
    }
}

// ------------------------------------------------- pass 1: chunked scan -----
__global__ void __launch_bounds__(256) scan_chunk(
    float* __restrict__ XBC,
    const float* __restrict__ DT,
    const float* __restrict__ bound,
    __hip_bfloat16* __restrict__ Cconv,   // B x L x 128
    __hip_bfloat16* __restrict__ Hend,    // (bh*NCH+g) x 64 x 128
    float* __restrict__ cbuf,             // bh x L
    const float* __restrict__ conv_w,
    const float* __restrict__ conv_b,
    const float* __restrict__ A_log,
    const float* __restrict__ Dskip,
    int eg)
{
    const int bx = blockIdx.x;
    const int h  = bx % NH;
    const int b  = (bx / NH) % BATCH;
    const int g  = bx / (NH * BATCH);
    const int t  = threadIdx.x;
    const int bh = b * NH + h;

    __shared__ float ring[4][320];
    __shared__ float cv[320];

    const int col1 = (t < 64) ? h*64 + t : 960 + t;
    const int col2 = 1216 + t;

    float w1[4], w2[4] = {0,0,0,0};
    #pragma unroll
    for (int j = 0; j < 4; ++j) w1[j] = conv_w[((size_t)eg*CONVD + col1)*4 + j];
    float b1 = conv_b[eg*CONVD + col1];
    float b2 = 0.f;
    if (t < 64) {
        #pragma unroll
        for (int j = 0; j < 4; ++j) w2[j] = conv_w[((size_t)eg*CONVD + col2)*4 + j];
        b2 = conv_b[eg*CONVD + col2];
    }
    const float Ah = -expf(A_log[eg*NH + h]);
    const float Dv = Dskip[eg*NH + h];

    const int l0 = g * CS, lend = l0 + CS;
    const size_t rowbase = (size_t)b * L_SEQ * CONVD;
    const size_t dtbase  = ((size_t)b * L_SEQ) * NH + h;

    {
        const float* bb = bound + ((size_t)(b*NCH + g)*3)*CONVD;
        #pragma unroll
        for (int k = 0; k < 3; ++k) {
            const int sl = (l0 - 3 + k) & 3;
            ring[sl][t] = bb[k*CONVD + col1];
            if (t < 64) ring[sl][256 + t] = bb[k*CONVD + col2];
        }
        const float* r0 = XBC + rowbase + (size_t)l0 * CONVD;
        ring[l0 & 3][t] = r0[col1];
        if (t < 64) ring[l0 & 3][256 + t] = r0[col2];
    }
    __syncthreads();

    const int p   = t >> 2;
    const int grp = t & 3;
    const int ns  = grp * 32;
    const int rot = grp * 8;
    float hreg[32];
    #pragma unroll
    for (int i = 0; i < 32; ++i) hreg[i] = 0.f;
    float c = 1.f;
    float dt_cur = DT[dtbase + (size_t)l0 * NH];

    for (int l = l0; l < lend; ++l) {
        const size_t rb = rowbase + (size_t)l * CONVD;
        float n1 = 0.f, n2 = 0.f, dtn = 0.f;
        if (l + 1 < lend) {
            const float* rn = XBC + rb + CONVD;
            n1 = rn[col1];
            if (t < 64) n2 = rn[col2];
            dtn = DT[dtbase + (size_t)(l+1) * NH];
        }
        {
            const int s0 = (l+1)&3, s1 = (l+2)&3, s2_ = (l+3)&3, s3 = l&3;
            float o1 = ring[s0][t]*w1[0] + ring[s1][t]*w1[1]
                     + ring[s2_][t]*w1[2] + ring[s3][t]*w1[3] + b1;
            cv[t] = siluf(o1);
            if (t < 64) {
                float o2 = ring[s0][256+t]*w2[0] + ring[s1][256+t]*w2[1]
                         + ring[s2_][256+t]*w2[2] + ring[s3][256+t]*w2[3] + b2;
                cv[256 + t] = siluf(o2);
            }
        }
        __syncthreads();
        if (h == 0 && t < 128)
            Cconv[((size_t)b*L_SEQ + l)*128 + t] = __float2bfloat16(cv[192 + t]);
        const float dA = expf(dt_cur * Ah);
        c *= dA;
        if (t == 0) cbuf[(size_t)bh*L_SEQ + l] = c;
        const float xp = cv[p];
        const float sx = dt_cur * xp;
        float ys = 0.f;
        #pragma unroll
        for (int i = 0; i < 32; ++i) {
            const int n = ns + ((i + rot) & 31);
            hreg[i] = hreg[i]*dA + sx*cv[64 + n];
            ys += hreg[i]*cv[192 + n];
        }
        ys += __shfl_xor(ys, 1);
        ys += __shfl_xor(ys, 2);
        if (l + 1 < lend) {
            const int sl = (l+1)&3;
            ring[sl][t] = n1;
            if (t < 64) ring[sl][256 + t] = n2;
        }
        if (grp == 0)
            XBC[rb + h*64 + p] = ys + xp*Dv;
        dt_cur = dtn;
        __syncthreads();
    }
    __hip_bfloat16* He = Hend + ((size_t)(bh*NCH + g)*64 + p)*128;
    #pragma unroll
    for (int i = 0; i < 32; ++i) {
        const int n = ns + ((i + rot) & 31);
        He[n] = __float2bfloat16(hreg[i]);
    }
}

// --------------------------------------- pass 2: chunk-state propagation ----
__global__ void __launch_bounds__(256) prop_kernel(
    __hip_bfloat16* __restrict__ Hend, const float* __restrict__ cbuf)
{
    const int bh = blockIdx.x;
    const int t  = threadIdx.x;
    const int p  = t >> 2;
    const int ns = (t & 3) * 32;
    float hs[32];
    #pragma unroll
    for (int j = 0; j < 32; ++j) hs[j] = 0.f;
    for (int g = 1; g < NCH; ++g) {
        const float ce = cbuf[(size_t)bh*L_SEQ + g*CS - 1];
        __hip_bfloat16* He = Hend + ((size_t)(bh*NCH + g-1)*64 + p)*128 + ns;
        #pragma unroll
        for (int j = 0; j < 32; ++j) {
            float he = __bfloat162float(He[j]);
            hs[j] = ce*hs[j] + he;
            He[j] = __float2bfloat16(hs[j]);
        }
    }
}

// --------------------------------------------- pass 3: y correction ---------
__global__ void __launch_bounds__(256) correct_kernel(
    float* __restrict__ XBC,
    const __hip_bfloat16* __restrict__ Cconv,
    const __hip_bfloat16* __restrict__ Hend,
    const float* __restrict__ cbuf)
{
    const int bx = blockIdx.x;
    const int g  = bx / (NH * BATCH);
    if (g == 0) return;
    const int h  = bx % NH;
    const int b  = (bx / NH) % BATCH;
    const int t  = threadIdx.x;
    const int bh = b * NH + h;
    const int p   = t >> 2;
    const int grp = t & 3;
    const int ns  = grp * 32;
    const int rot = grp * 8;

    __shared__ float cvC[128];

    const __hip_bfloat16* He = Hend + ((size_t)(bh*NCH + g-1)*64 + p)*128;
    float h0[32];
    #pragma unroll
    for (int i = 0; i < 32; ++i) h0[i] = __bfloat162float(He[ns + ((i + rot) & 31)]);

    const int l0 = g * CS, lend = l0 + CS;
    const size_t rowbase = (size_t)b * L_SEQ * CONVD;
    for (int l = l0; l < lend; ++l) {
        if (t < 128) cvC[t] = __bfloat162float(Cconv[((size_t)b*L_SEQ + l)*128 + t]);
        __syncthreads();
        const float cl = cbuf[(size_t)bh*L_SEQ + l];
        float s = 0.f;
        #pragma unroll
        for (int i = 0; i < 32; ++i)
            s += h0[i] * cvC[ns + ((i + rot) & 31)];
        s += __shfl_xor(s, 1);
        s += __shfl_xor(s, 2);
        if (grp == 0)
            XBC[rowbase + (size_t)l*CONVD + h*64 + p] += cl * s;
        __syncthreads();
    }
}

// ------------------------------------------------------- gated RMS norm -----
__global__ void __launch_bounds__(256) norm_kernel(
    float* __restrict__ Ybuf,          // rows, stride 1280, in-place
    const float* __restrict__ Z,       // rows x 1024
    const float* __restrict__ nw)      // 1024
{
    const int row = blockIdx.x;
    const int t = threadIdx.x;
    float* y = Ybuf + (size_t)row * CONVD;
    const float* z = Z + (size_t)row * DINNER;

    float4 yv = *(const float4*)(y + t*4);
    float4 zv = *(const float4*)(z + t*4);
    float v[4]; float ss = 0.f;
    #pragma unroll
    for (int j = 0; j < 4; ++j) {
        float zz = ((const float*)&zv)[j];
        float vv = ((const float*)&yv)[j] * siluf(zz);
        v[j] = vv; ss += vv*vv;
    }
    #pragma unroll
    for (int o = 32; o > 0; o >>= 1) ss += __shfl_down(ss, o);
    __shared__ float wsum[4];
    if ((t & 63) == 0) wsum[t >> 6] = ss;
    __syncthreads();
    const float total = wsum[0] + wsum[1] + wsum[2] + wsum[3];
    const float scale = rsqrtf(total / (float)DINNER + 1e-5f);
    float4 ov;
    #pragma unroll
    for (int j = 0; j < 4; ++j) ((float*)&ov)[j] = v[j] * scale * nw[t*4 + j];
    *(float4*)(y + t*4) = ov;
}

// ------------------------------------------------------------------ host ----
extern "C" void kernel_launch(void* const* d_in, const int* in_sizes, int n_in,
                              void* d_out, int out_size, void* d_ws, size_t ws_size,
                              hipStream_t stream)
{
    const float* x        = (const float*)d_in[0];
    const float* gate_w   = (const float*)d_in[1];
    const float* gate_b   = (const float*)d_in[2];
    const float* gate_n   = (const float*)d_in[3];
    const float* in_w     = (const float*)d_in[4];
    const float* conv_w   = (const float*)d_in[5];
    const float* conv_b   = (const float*)d_in[6];
    const float* dt_bias  = (const float*)d_in[7];
    const float* A_log    = (const float*)d_in[8];
    const float* Dskip    = (const float*)d_in[9];
    const float* norm_w   = (const float*)d_in[10];
    const float* out_w    = (const float*)d_in[11];
    float* out = (float*)d_out;

    // workspace layout (float units); total 61.9 MB (proven-safe <= 63.5 MB)
    float* XBC   = (float*)d_ws;                    // 10,240,000
    float* DTb   = XBC  + (size_t)10240000;         //    128,000
    float* HendF = DTb  + (size_t)128000;           //  4,194,304 (bf16 x 8.39M)
    float* cbuf  = HendF + (size_t)4194304;         //    128,000
    float* CconF = cbuf + (size_t)128000;           //    512,000 (bf16 x 1.02M)
    float* bound = CconF + (size_t)512000;          //    245,760
    float* maskb = bound + (size_t)245760;          //     32,000
    float* Ztile = HendF;                           //  2,048,000 (alias dead Hend)
    __hip_bfloat16* Hend  = (__hip_bfloat16*)HendF;
    __hip_bfloat16* Cconv = (__hip_bfloat16*)CconF;

    gate_kernel<<<M_TOK, 64, 0, stream>>>(x, gate_w, gate_b, gate_n, maskb);

    for (int e = 0; e < NEXP; ++e) {
        const float* Wb = in_w + (size_t)e * DIN_ALL * DMODEL;
        // xBC = X @ Wi[1024:2304]^T  (bf16 MFMA)
        gemm_bf16<0><<<dim3(10, 63), 256, 0, stream>>>(
            x, DMODEL, M_TOK, Wb + (size_t)1024*DMODEL, DMODEL,
            XBC, nullptr, 0, 0);
        // dt (f32)
        dt_kernel<<<M_TOK, 256, 0, stream>>>(
            x, Wb + (size_t)2304*DMODEL, dt_bias + e*NH, DTb);
        stash_kernel<<<BATCH*NCH, 256, 0, stream>>>(XBC, bound);
        scan_chunk<<<NCH*BATCH*NH, 256, 0, stream>>>(
            XBC, DTb, bound, Cconv, Hend, cbuf,
            conv_w, conv_b, A_log, Dskip, e);
        prop_kernel<<<BATCH*NH, 256, 0, stream>>>(Hend, cbuf);
        correct_kernel<<<NCH*BATCH*NH, 256, 0, stream>>>(XBC, Cconv, Hend, cbuf);
        for (int mt = 0; mt < 4; ++mt) {
            gemm_bf16<1><<<dim3(8, 16), 256, 0, stream>>>(
                x + (size_t)mt*2000*DMODEL, DMODEL, 2000, Wb, DMODEL,
                Ztile, nullptr, 0, 0);
            norm_kernel<<<2000, 256, 0, stream>>>(
                XBC + (size_t)mt*2000*CONVD, Ztile, norm_w + (size_t)e*DINNER);
        }
        gemm_bf16<2><<<dim3(4, 63), 256, 0, stream>>>(
            XBC, CONVD, M_TOK, out_w + (size_t)e*DMODEL*DINNER, DINNER,
            out, maskb, e, e == 0 ? 1 : 0);
    }
}

// Round 5
// 1495.146 us; speedup vs baseline: 6.0334x; 1.8771x over previous
//
#include <hip/hip_runtime.h>
#include <hip/hip_bf16.h>

#define M_TOK   8000
#define L_SEQ   2000
#define BATCH   4
#define NEXP    4
#define NH      16
#define HD      64
#define DSTATE  128
#define DMODEL  512
#define DINNER  1024
#define CONVD   1280
#define DIN_ALL 2320   // 1024 z + 1280 xBC + 16 dt
#define TCH     128    // SSD chunk length
#define NC      16     // chunks per sequence (TCH*NC >= L_SEQ)
#define LPAD    136    // LDS row pitch (shorts): 16B-aligned, 2-way banks

typedef __attribute__((ext_vector_type(8))) short short8;
typedef __attribute__((ext_vector_type(4))) float f32x4;
typedef unsigned short u16;

__device__ __forceinline__ float siluf(float v) {
    return v / (1.f + __expf(-v));
}
__device__ __forceinline__ float softplusf(float v) {
    return v > 20.f ? v : log1pf(expf(v));
}
__device__ __forceinline__ u16 f2bf(float f) {
    union { float f; unsigned u; } x; x.f = f;
    return (u16)((x.u + 0x7fffu + ((x.u >> 16) & 1u)) >> 16);
}
__device__ __forceinline__ float bf2f(u16 v) {
    union { unsigned u; float f; } x; x.u = ((unsigned)v) << 16; return x.f;
}

// ---------------------------------------------------------------- gating ----
__global__ void __launch_bounds__(64) gate_kernel(
    const float* __restrict__ X, const float* __restrict__ GW,
    const float* __restrict__ GB, const float* __restrict__ GN,
    float* __restrict__ mask)
{
    const int m = blockIdx.x;
    const int t = threadIdx.x;
    const float* x = X + (size_t)m * DMODEL;
    float s0 = 0.f, s1 = 0.f, s2 = 0.f, s3 = 0.f;
    for (int k = t; k < DMODEL; k += 64) {
        float xv = x[k];
        s0 += xv * GW[k];
        s1 += xv * GW[512 + k];
        s2 += xv * GW[1024 + k];
        s3 += xv * GW[1536 + k];
    }
    #pragma unroll
    for (int o = 32; o > 0; o >>= 1) {
        s0 += __shfl_down(s0, o);
        s1 += __shfl_down(s1, o);
        s2 += __shfl_down(s2, o);
        s3 += __shfl_down(s3, o);
    }
    if (t == 0) {
        float lg[4] = { s0 + GB[0] + GN[m*4+0]*0.01f,
                        s1 + GB[1] + GN[m*4+1]*0.01f,
                        s2 + GB[2] + GN[m*4+2]*0.01f,
                        s3 + GB[3] + GN[m*4+3]*0.01f };
        float mx = fmaxf(fmaxf(lg[0], lg[1]), fmaxf(lg[2], lg[3]));
        float p[4]; float sum = 0.f;
        #pragma unroll
        for (int e = 0; e < 4; ++e) { p[e] = expf(lg[e] - mx); sum += p[e]; }
        #pragma unroll
        for (int e = 0; e < 4; ++e) p[e] /= sum;
        int i0 = 0;
        #pragma unroll
        for (int e = 1; e < 4; ++e) if (p[e] > p[i0]) i0 = e;
        int i1 = -1;
        #pragma unroll
        for (int e = 0; e < 4; ++e) {
            if (e == i0) continue;
            if (i1 < 0 || p[e] > p[i1]) i1 = e;
        }
        float s2v = p[i0] + p[i1];
        #pragma unroll
        for (int e = 0; e < 4; ++e)
            mask[m*4 + e] = (e == i0 || e == i1) ? p[e] / s2v : 0.f;
    }
}

// --------------------------------------------------------- bf16 MFMA GEMM ---
// OUT[M x N] = A(M x K, stride lda) @ B(f32, N x K row-major)^T
// MODE 0: OUT=XBC raw f32 (stride 1280). MODE 1: OUT=Ztile f32 (stride 1024).
// MODE 2: out[m*512+n] (+)= mask[m*4+e] * acc  (A is bf16 when ABF16).
template<int MODE, bool ABF16>
__global__ void __launch_bounds__(256) gemm_bf16(
    const void* __restrict__ Araw, int lda, int Mrows,
    const float* __restrict__ B, int K,
    float* __restrict__ OUT,
    const float* __restrict__ mask, int e, int first)
{
    __shared__ u16 As[128][40];
    __shared__ u16 Bs[128][40];
    const int t  = threadIdx.x;
    const int m0 = blockIdx.y * 128;
    const int n0 = blockIdx.x * 128;
    const int w  = t >> 6, l = t & 63;
    const int wm = (w >> 1) * 64, wn = (w & 1) * 64;
    const int srow = t >> 1;
    const int scol = (t & 1) * 16;

    f32x4 acc[4][4];
    #pragma unroll
    for (int i = 0; i < 4; ++i)
        #pragma unroll
        for (int j = 0; j < 4; ++j) {
            acc[i][j][0] = 0.f; acc[i][j][1] = 0.f;
            acc[i][j][2] = 0.f; acc[i][j][3] = 0.f;
        }

    int arow = m0 + srow; if (arow >= Mrows) arow = Mrows - 1;
    const float* Af = (const float*)Araw;
    const u16*   Ab = (const u16*)Araw;
    const float* Bptr = B + (size_t)(n0 + srow) * K + scol;

    for (int k0 = 0; k0 < K; k0 += 32) {
        if (ABF16) {
            short8 v0 = *(const short8*)(Ab + (size_t)arow * lda + scol + k0);
            short8 v1 = *(const short8*)(Ab + (size_t)arow * lda + scol + k0 + 8);
            *(short8*)&As[srow][scol]     = v0;
            *(short8*)&As[srow][scol + 8] = v1;
        } else {
            const float* Ap = Af + (size_t)arow * lda + scol + k0;
            float4 a0 = *(const float4*)(Ap);
            float4 a1 = *(const float4*)(Ap + 4);
            float4 a2 = *(const float4*)(Ap + 8);
            float4 a3 = *(const float4*)(Ap + 12);
            short8 pa, pa2;
            pa[0]=f2bf(a0.x); pa[1]=f2bf(a0.y); pa[2]=f2bf(a0.z); pa[3]=f2bf(a0.w);
            pa[4]=f2bf(a1.x); pa[5]=f2bf(a1.y); pa[6]=f2bf(a1.z); pa[7]=f2bf(a1.w);
            pa2[0]=f2bf(a2.x); pa2[1]=f2bf(a2.y); pa2[2]=f2bf(a2.z); pa2[3]=f2bf(a2.w);
            pa2[4]=f2bf(a3.x); pa2[5]=f2bf(a3.y); pa2[6]=f2bf(a3.z); pa2[7]=f2bf(a3.w);
            *(short8*)&As[srow][scol]     = pa;
            *(short8*)&As[srow][scol + 8] = pa2;
        }
        {
            float4 b0 = *(const float4*)(Bptr + k0);
            float4 b1 = *(const float4*)(Bptr + k0 + 4);
            float4 b2 = *(const float4*)(Bptr + k0 + 8);
            float4 b3 = *(const float4*)(Bptr + k0 + 12);
            short8 pb, pb2;
            pb[0]=f2bf(b0.x); pb[1]=f2bf(b0.y); pb[2]=f2bf(b0.z); pb[3]=f2bf(b0.w);
            pb[4]=f2bf(b1.x); pb[5]=f2bf(b1.y); pb[6]=f2bf(b1.z); pb[7]=f2bf(b1.w);
            pb2[0]=f2bf(b2.x); pb2[1]=f2bf(b2.y); pb2[2]=f2bf(b2.z); pb2[3]=f2bf(b2.w);
            pb2[4]=f2bf(b3.x); pb2[5]=f2bf(b3.y); pb2[6]=f2bf(b3.z); pb2[7]=f2bf(b3.w);
            *(short8*)&Bs[srow][scol]     = pb;
            *(short8*)&Bs[srow][scol + 8] = pb2;
        }
        __syncthreads();

        short8 af[4], bfr[4];
        const int ko = (l >> 4) * 8;
        #pragma unroll
        for (int i = 0; i < 4; ++i) {
            af[i]  = *(const short8*)&As[wm + i*16 + (l & 15)][ko];
            bfr[i] = *(const short8*)&Bs[wn + i*16 + (l & 15)][ko];
        }
        #pragma unroll
        for (int i = 0; i < 4; ++i)
            #pragma unroll
            for (int j = 0; j < 4; ++j)
                acc[i][j] = __builtin_amdgcn_mfma_f32_16x16x32_bf16(
                    af[i], bfr[j], acc[i][j], 0, 0, 0);
        __syncthreads();
    }

    #pragma unroll
    for (int i = 0; i < 4; ++i) {
        #pragma unroll
        for (int r = 0; r < 4; ++r) {
            const int m = m0 + wm + i*16 + (l >> 4)*4 + r;
            if (m >= Mrows) continue;
            float wgt = 0.f;
            if (MODE == 2) wgt = mask[m*4 + e];
            #pragma unroll
            for (int j = 0; j < 4; ++j) {
                const int n = n0 + wn + j*16 + (l & 15);
                const float v = acc[i][j][r];
                if (MODE == 0) {
                    OUT[(size_t)m*CONVD + n] = v;
                } else if (MODE == 1) {
                    OUT[(size_t)m*DINNER + n] = v;
                } else {
                    const size_t o = (size_t)m*DMODEL + n;
                    const float xv = wgt * v;
                    OUT[o] = first ? xv : OUT[o] + xv;
                }
            }
        }
    }
}

// ------------------------------------------------------------- dt GEMV f32 --
__global__ void __launch_bounds__(256) dt_kernel(
    const float* __restrict__ X,
    const float* __restrict__ Wd,    // 16 x 512 (dt rows of in_proj)
    const float* __restrict__ dtb,   // 16
    float* __restrict__ DT)          // M x 16
{
    const int m = blockIdx.x;
    const int t = threadIdx.x;
    __shared__ float xs[512];
    xs[t] = X[(size_t)m*DMODEL + t];
    xs[t + 256] = X[(size_t)m*DMODEL + 256 + t];
    __syncthreads();
    const int w = t >> 6, l = t & 63;
    #pragma unroll
    for (int q = 0; q < 4; ++q) {
        const int hh = w*4 + q;
        const float* wr = Wd + (size_t)hh * DMODEL;
        float s = 0.f;
        for (int k = l; k < DMODEL; k += 64) s += xs[k] * wr[k];
        #pragma unroll
        for (int o = 32; o > 0; o >>= 1) s += __shfl_xor(s, o);
        if (l == 0) DT[(size_t)m*NH + hh] = softplusf(s + dtb[hh]);
    }
}

// ---------------------------------------------------- conv4 + SiLU pre-pass -
// XCONV(bf16) = silu(causal_conv4(XBC raw) + bias), all 1280 channels.
__global__ void __launch_bounds__(256) conv_kernel(
    const float* __restrict__ XBC,   // M x 1280 raw
    u16* __restrict__ XCONV,         // M x 1280 bf16
    const float* __restrict__ conv_w,
    const float* __restrict__ conv_b,
    int eg)
{
    const int cg = blockIdx.x;       // 0..3 col group of 320
    const int lt = blockIdx.y;       // 0..62 row tile of 32
    const int b  = blockIdx.z;
    const int t  = threadIdx.x;
    const int l0 = lt * 32, cbase = cg * 320;

    __shared__ float raw[35][320];
    __shared__ float cw[320][4];
    __shared__ float cb[320];

    for (int idx = t; idx < 35*320; idx += 256) {
        const int r = idx / 320, c = idx - r*320;
        const int l = l0 - 3 + r;
        raw[r][c] = (l >= 0 && l < L_SEQ)
            ? XBC[((size_t)b*L_SEQ + l)*CONVD + cbase + c] : 0.f;
    }
    for (int c = t; c < 320; c += 256) {
        #pragma unroll
        for (int k = 0; k < 4; ++k)
            cw[c][k] = conv_w[((size_t)eg*CONVD + cbase + c)*4 + k];
        cb[c] = conv_b[eg*CONVD + cbase + c];
    }
    __syncthreads();
    for (int idx = t; idx < 32*320; idx += 256) {
        const int ro = idx / 320, c = idx - ro*320;
        const int l = l0 + ro;
        if (l >= L_SEQ) continue;
        float v = raw[ro][c]*cw[c][0] + raw[ro+1][c]*cw[c][1]
                + raw[ro+2][c]*cw[c][2] + raw[ro+3][c]*cw[c][3] + cb[c];
        XCONV[((size_t)b*L_SEQ + l)*CONVD + cbase + c] = f2bf(siluf(v));
    }
}

// --------------------------------------------------- SSD pass 1 (per chunk) -
// One block per (g,h,b): S=C@B^T, P=mask*exp*dt, Y1=P@X (+D*x) -> y in XCONV,
// Hloc=(B^T*w)@X -> Hend, chunk decay -> cbuf, chunk-local cumsum -> Acum.
__global__ void __launch_bounds__(512) ssd1_kernel(
    u16* __restrict__ XCONV,
    const float* __restrict__ DT,
    float* __restrict__ Acum,          // bh x 2000
    u16* __restrict__ Hend,            // (bh*NC+g) x 128 x 64
    float* __restrict__ cbuf,          // bh*NC+g
    const float* __restrict__ A_log,
    const float* __restrict__ Dskip,
    int eg)
{
    const int g = blockIdx.x, h = blockIdx.y, b = blockIdx.z;
    const int t = threadIdx.x;
    const int ln = t & 63, w = t >> 6;
    const int bh = b*NH + h;
    const int l0 = g * TCH;

    __shared__ u16 Bc[TCH][LPAD];
    __shared__ u16 Cc[TCH][LPAD];
    __shared__ u16 Xt[HD][LPAD];
    __shared__ u16 Pb[TCH][LPAD];
    __shared__ float ac[TCH], wj[TCH], dtb[TCH];

    const float Ah = -__expf(A_log[eg*NH + h]);
    const float Dv = Dskip[eg*NH + h];

    // ---- stage B, C, X^T, dt ----
    {
        const int i = t >> 2, q = t & 3;
        const bool v = (l0 + i) < L_SEQ;
        const u16* src = XCONV + (size_t)(b*L_SEQ + l0 + i) * CONVD;
        const short8 z8 = {0,0,0,0,0,0,0,0};
        #pragma unroll
        for (int u = 0; u < 4; ++u) {
            short8 bv = v ? *(const short8*)(src + 1024 + q*32 + u*8) : z8;
            short8 cv = v ? *(const short8*)(src + 1152 + q*32 + u*8) : z8;
            *(short8*)&Bc[i][q*32 + u*8] = bv;
            *(short8*)&Cc[i][q*32 + u*8] = cv;
        }
        #pragma unroll
        for (int u = 0; u < 2; ++u) {
            short8 xv = v ? *(const short8*)(src + h*HD + q*16 + u*8) : z8;
            #pragma unroll
            for (int k = 0; k < 8; ++k)
                Xt[q*16 + u*8 + k][i] = ((const u16*)&xv)[k];
        }
        if (t < TCH) {
            const int l = l0 + t;
            dtb[t] = (l < L_SEQ) ? DT[(size_t)(b*L_SEQ + l)*NH + h] : 0.f;
        }
    }
    __syncthreads();

    // ---- inclusive cumsum of s=dt*Ah (wave 0) ----
    if (w == 0) {
        float s0 = dtb[ln] * Ah;
        float s1 = dtb[64 + ln] * Ah;
        #pragma unroll
        for (int o = 1; o < 64; o <<= 1) {
            float v0 = __shfl_up(s0, o);
            float v1 = __shfl_up(s1, o);
            if (ln >= o) { s0 += v0; s1 += v1; }
        }
        s1 += __shfl(s0, 63);
        const float acT = __shfl(s1, 63);
        ac[ln] = s0; ac[64 + ln] = s1;
        wj[ln]      = __expf(acT - s0) * dtb[ln];
        wj[64 + ln] = __expf(acT - s1) * dtb[64 + ln];
        if (l0 + ln < L_SEQ)      Acum[(size_t)bh*L_SEQ + l0 + ln] = s0;
        if (l0 + 64 + ln < L_SEQ) Acum[(size_t)bh*L_SEQ + l0 + 64 + ln] = s1;
        if (ln == 63) cbuf[bh*NC + g] = __expf(acT);
    }
    __syncthreads();

    // ---- S = Cc @ Bc^T (rows w*16..w*16+15) ----
    f32x4 sacc[8];
    #pragma unroll
    for (int c = 0; c < 8; ++c) { sacc[c][0]=0.f; sacc[c][1]=0.f; sacc[c][2]=0.f; sacc[c][3]=0.f; }
    #pragma unroll
    for (int ks = 0; ks < 4; ++ks) {
        short8 afr = *(const short8*)&Cc[w*16 + (ln & 15)][ks*32 + (ln >> 4)*8];
        #pragma unroll
        for (int ct = 0; ct < 8; ++ct) {
            short8 bfr = *(const short8*)&Bc[ct*16 + (ln & 15)][ks*32 + (ln >> 4)*8];
            sacc[ct] = __builtin_amdgcn_mfma_f32_16x16x32_bf16(afr, bfr, sacc[ct], 0, 0, 0);
        }
    }
    // ---- P = mask(j<=i) * S * exp(ac_i - ac_j) * dt_j ----
    {
        const int i0 = w*16 + (ln >> 4)*4;
        float aci[4];
        #pragma unroll
        for (int r = 0; r < 4; ++r) aci[r] = ac[i0 + r];
        #pragma unroll
        for (int ct = 0; ct < 8; ++ct) {
            const int j = ct*16 + (ln & 15);
            const float acj = ac[j], dtj = dtb[j];
            #pragma unroll
            for (int r = 0; r < 4; ++r) {
                const int i2 = i0 + r;
                float pv = (j <= i2) ? sacc[ct][r] * __expf(aci[r] - acj) * dtj : 0.f;
                Pb[i2][j] = f2bf(pv);
            }
        }
    }
    __syncthreads();

    // ---- Y1 = P @ X (+ D*x) -> y (bf16, in place over x-cols) ----
    {
        f32x4 yacc[4];
        #pragma unroll
        for (int p = 0; p < 4; ++p) { yacc[p][0]=0.f; yacc[p][1]=0.f; yacc[p][2]=0.f; yacc[p][3]=0.f; }
        #pragma unroll
        for (int ks = 0; ks < 4; ++ks) {
            short8 afr = *(const short8*)&Pb[w*16 + (ln & 15)][ks*32 + (ln >> 4)*8];
            #pragma unroll
            for (int pt = 0; pt < 4; ++pt) {
                short8 bfr = *(const short8*)&Xt[pt*16 + (ln & 15)][ks*32 + (ln >> 4)*8];
                yacc[pt] = __builtin_amdgcn_mfma_f32_16x16x32_bf16(afr, bfr, yacc[pt], 0, 0, 0);
            }
        }
        #pragma unroll
        for (int pt = 0; pt < 4; ++pt) {
            const int p = pt*16 + (ln & 15);
            #pragma unroll
            for (int r = 0; r < 4; ++r) {
                const int i2 = w*16 + (ln >> 4)*4 + r;
                const int lg = l0 + i2;
                if (lg < L_SEQ) {
                    const float xv = bf2f(Xt[p][i2]);
                    XCONV[(size_t)(b*L_SEQ + lg)*CONVD + h*HD + p] =
                        f2bf(yacc[pt][r] + Dv * xv);
                }
            }
        }
    }

    // ---- Hloc = (Bc^T scaled by wj) @ X -> Hend[n][p] ----
    {
        f32x4 hacc[4];
        #pragma unroll
        for (int p = 0; p < 4; ++p) { hacc[p][0]=0.f; hacc[p][1]=0.f; hacc[p][2]=0.f; hacc[p][3]=0.f; }
        #pragma unroll
        for (int ks = 0; ks < 4; ++ks) {
            const int jb = ks*32 + (ln >> 4)*8;
            const int nr = w*16 + (ln & 15);
            short8 afr;
            #pragma unroll
            for (int jj = 0; jj < 8; ++jj)
                afr[jj] = (short)f2bf(bf2f(Bc[jb + jj][nr]) * wj[jb + jj]);
            #pragma unroll
            for (int pt = 0; pt < 4; ++pt) {
                short8 bfr = *(const short8*)&Xt[pt*16 + (ln & 15)][jb];
                hacc[pt] = __builtin_amdgcn_mfma_f32_16x16x32_bf16(afr, bfr, hacc[pt], 0, 0, 0);
            }
        }
        u16* Hb = Hend + (size_t)(bh*NC + g) * (TCH*HD);
        #pragma unroll
        for (int pt = 0; pt < 4; ++pt)
            #pragma unroll
            for (int r = 0; r < 4; ++r) {
                const int n = w*16 + (ln >> 4)*4 + r;
                Hb[n*HD + pt*16 + (ln & 15)] = f2bf(hacc[pt][r]);
            }
    }
}

// --------------------------------------- pass 2: chunk-state propagation ----
// slot[g] <- h_start[g+1] = cbuf[g]*h_start[g] + Hloc[g]
__global__ void __launch_bounds__(256) prop_kernel(
    u16* __restrict__ Hend, const float* __restrict__ cbuf)
{
    const int bh = blockIdx.x;
    const int t  = threadIdx.x;
    float hs[32];
    #pragma unroll
    for (int j = 0; j < 32; ++j) hs[j] = 0.f;
    for (int g = 0; g < NC - 1; ++g) {
        const float ce = cbuf[bh*NC + g];
        u16* He = Hend + (size_t)(bh*NC + g)*(TCH*HD) + t*32;
        #pragma unroll
        for (int j = 0; j < 32; ++j) {
            const float lo = bf2f(He[j]);
            hs[j] = ce*hs[j] + lo;
            He[j] = f2bf(hs[j]);
        }
    }
}

// --------------------------------------------- pass 3: Y2 = Cs @ h_start ----
__global__ void __launch_bounds__(256) ssd2_kernel(
    u16* __restrict__ XCONV,
    const float* __restrict__ Acum,
    const u16* __restrict__ Hend)
{
    const int g = blockIdx.x, h = blockIdx.y, b = blockIdx.z;
    if (g == 0) return;
    const int t = threadIdx.x, ln = t & 63, w = t >> 6;
    const int bh = b*NH + h;
    const int l0 = g * TCH;

    __shared__ u16 Cs[TCH][LPAD];
    __shared__ u16 Ht[HD][LPAD];

    {   // stage Cs[i][n] = Cc[i][n] * exp(ac_i)
        const int i = t >> 1, q = t & 1;
        const bool v = (l0 + i) < L_SEQ;
        const float eaci = v ? __expf(Acum[(size_t)bh*L_SEQ + l0 + i]) : 0.f;
        const u16* src = XCONV + (size_t)(b*L_SEQ + l0 + i)*CONVD + 1152 + q*64;
        const short8 z8 = {0,0,0,0,0,0,0,0};
        #pragma unroll
        for (int u = 0; u < 8; ++u) {
            short8 cv = v ? *(const short8*)(src + u*8) : z8;
            short8 ov;
            #pragma unroll
            for (int k = 0; k < 8; ++k)
                ov[k] = (short)f2bf(bf2f(((const u16*)&cv)[k]) * eaci);
            *(short8*)&Cs[i][q*64 + u*8] = ov;
        }
    }
    {   // stage Ht[p][n] = H0[n][p]
        const u16* Hb = Hend + (size_t)(bh*NC + g - 1)*(TCH*HD) + t*32;
        #pragma unroll
        for (int k = 0; k < 32; ++k) {
            const int idx = t*32 + k;
            Ht[idx & 63][idx >> 6] = Hb[k];
        }
    }
    __syncthreads();

    f32x4 acc2[2][4];
    #pragma unroll
    for (int rt = 0; rt < 2; ++rt)
        #pragma unroll
        for (int pt = 0; pt < 4; ++pt) { acc2[rt][pt][0]=0.f; acc2[rt][pt][1]=0.f; acc2[rt][pt][2]=0.f; acc2[rt][pt][3]=0.f; }
    #pragma unroll
    for (int ks = 0; ks < 4; ++ks) {
        short8 af0 = *(const short8*)&Cs[w*32 +      (ln & 15)][ks*32 + (ln >> 4)*8];
        short8 af1 = *(const short8*)&Cs[w*32 + 16 + (ln & 15)][ks*32 + (ln >> 4)*8];
        #pragma unroll
        for (int pt = 0; pt < 4; ++pt) {
            short8 bfr = *(const short8*)&Ht[pt*16 + (ln & 15)][ks*32 + (ln >> 4)*8];
            acc2[0][pt] = __builtin_amdgcn_mfma_f32_16x16x32_bf16(af0, bfr, acc2[0][pt], 0, 0, 0);
            acc2[1][pt] = __builtin_amdgcn_mfma_f32_16x16x32_bf16(af1, bfr, acc2[1][pt], 0, 0, 0);
        }
    }
    #pragma unroll
    for (int rt = 0; rt < 2; ++rt)
        #pragma unroll
        for (int pt = 0; pt < 4; ++pt)
            #pragma unroll
            for (int r = 0; r < 4; ++r) {
                const int i2 = w*32 + rt*16 + (ln >> 4)*4 + r;
                const int lg = l0 + i2;
                if (lg < L_SEQ) {
                    u16* yp = XCONV + (size_t)(b*L_SEQ + lg)*CONVD + h*HD + pt*16 + (ln & 15);
                    *yp = f2bf(bf2f(*yp) + acc2[rt][pt][r]);
                }
            }
}

// ------------------------------------------------- gated RMS norm (bf16 y) --
__global__ void __launch_bounds__(256) norm_kernel(
    u16* __restrict__ Ybuf,            // rows, stride 1280 (bf16), in-place
    const float* __restrict__ Z,       // rows x 1024 f32
    const float* __restrict__ nw)      // 1024
{
    const int row = blockIdx.x;
    const int t = threadIdx.x;
    u16* y = Ybuf + (size_t)row * CONVD;
    const float* z = Z + (size_t)row * DINNER;

    ushort4 yv = *(const ushort4*)(y + t*4);
    float4 zv = *(const float4*)(z + t*4);
    float v[4]; float ss = 0.f;
    #pragma unroll
    for (int j = 0; j < 4; ++j) {
        const float zz = ((const float*)&zv)[j];
        const float vv = bf2f(((const u16*)&yv)[j]) * siluf(zz);
        v[j] = vv; ss += vv*vv;
    }
    #pragma unroll
    for (int o = 32; o > 0; o >>= 1) ss += __shfl_down(ss, o);
    __shared__ float wsum[4];
    if ((t & 63) == 0) wsum[t >> 6] = ss;
    __syncthreads();
    const float total = wsum[0] + wsum[1] + wsum[2] + wsum[3];
    const float scale = rsqrtf(total / (float)DINNER + 1e-5f);
    ushort4 ov;
    #pragma unroll
    for (int j = 0; j < 4; ++j)
        ((u16*)&ov)[j] = f2bf(v[j] * scale * nw[t*4 + j]);
    *(ushort4*)(y + t*4) = ov;
}

// ------------------------------------------------------------------ host ----
extern "C" void kernel_launch(void* const* d_in, const int* in_sizes, int n_in,
                              void* d_out, int out_size, void* d_ws, size_t ws_size,
                              hipStream_t stream)
{
    const float* x        = (const float*)d_in[0];
    const float* gate_w   = (const float*)d_in[1];
    const float* gate_b   = (const float*)d_in[2];
    const float* gate_n   = (const float*)d_in[3];
    const float* in_w     = (const float*)d_in[4];
    const float* conv_w   = (const float*)d_in[5];
    const float* conv_b   = (const float*)d_in[6];
    const float* dt_bias  = (const float*)d_in[7];
    const float* A_log    = (const float*)d_in[8];
    const float* Dskip    = (const float*)d_in[9];
    const float* norm_w   = (const float*)d_in[10];
    const float* out_w    = (const float*)d_in[11];
    float* out = (float*)d_out;

    char* ws = (char*)d_ws;
    // [0, 40.96MB): raw XBC f32; after conv -> Hend (16.78MB) + Ztile (8.2MB @20.48MB)
    float* XBCraw = (float*)ws;
    u16*   Hend   = (u16*)ws;
    float* Ztile  = (float*)(ws + 20480000);
    u16*   XCONV  = (u16*)(ws + 40960000);          // 20.48MB bf16
    float* DTb    = (float*)(ws + 61440000);        // 512KB
    float* Acum   = (float*)(ws + 61952000);        // 512KB
    float* cbuf   = (float*)(ws + 62464000);        // 4KB
    float* maskb  = (float*)(ws + 62468096);        // 128KB
    // total 62.6MB (< 63.5MB proven-safe)

    gate_kernel<<<M_TOK, 64, 0, stream>>>(x, gate_w, gate_b, gate_n, maskb);

    for (int e = 0; e < NEXP; ++e) {
        const float* Wb = in_w + (size_t)e * DIN_ALL * DMODEL;
        // raw xBC = X @ Wi[1024:2304]^T
        gemm_bf16<0, false><<<dim3(10, 63), 256, 0, stream>>>(
            x, DMODEL, M_TOK, Wb + (size_t)1024*DMODEL, DMODEL,
            XBCraw, nullptr, 0, 0);
        dt_kernel<<<M_TOK, 256, 0, stream>>>(
            x, Wb + (size_t)2304*DMODEL, dt_bias + e*NH, DTb);
        conv_kernel<<<dim3(4, 63, BATCH), 256, 0, stream>>>(
            XBCraw, XCONV, conv_w, conv_b, e);
        ssd1_kernel<<<dim3(NC, NH, BATCH), 512, 0, stream>>>(
            XCONV, DTb, Acum, Hend, cbuf, A_log, Dskip, e);
        prop_kernel<<<BATCH*NH, 256, 0, stream>>>(Hend, cbuf);
        ssd2_kernel<<<dim3(NC, NH, BATCH), 256, 0, stream>>>(
            XCONV, Acum, Hend);
        for (int mt = 0; mt < 4; ++mt) {
            gemm_bf16<1, false><<<dim3(8, 16), 256, 0, stream>>>(
                x + (size_t)mt*2000*DMODEL, DMODEL, 2000, Wb, DMODEL,
                Ztile, nullptr, 0, 0);
            norm_kernel<<<2000, 256, 0, stream>>>(
                XCONV + (size_t)mt*2000*CONVD, Ztile, norm_w + (size_t)e*DINNER);
        }
        gemm_bf16<2, true><<<dim3(4, 63), 256, 0, stream>>>(
            XCONV, CONVD, M_TOK, out_w + (size_t)e*DMODEL*DINNER, DINNER,
            out, maskb, e, e == 0 ? 1 : 0);
    }
}

// Round 6
// 1092.156 us; speedup vs baseline: 8.2597x; 1.3690x over previous
//
#include <hip/hip_runtime.h>
#include <hip/hip_bf16.h>

#define M_TOK   8000
#define L_SEQ   2000
#define BATCH   4
#define NEXP    4
#define NH      16
#define HD      64
#define DSTATE  128
#define DMODEL  512
#define DINNER  1024
#define CONVD   1280
#define DIN_ALL 2320   // 1024 z + 1280 xBC + 16 dt
#define TCH     128    // SSD chunk length
#define NC      16     // chunks per sequence
#define LPAD    136    // LDS row pitch (shorts) for SSD tiles

typedef __attribute__((ext_vector_type(8))) short short8;
typedef __attribute__((ext_vector_type(4))) float f32x4;
typedef unsigned short u16;

__device__ __forceinline__ float siluf(float v) {
    return v / (1.f + __expf(-v));
}
__device__ __forceinline__ float softplusf(float v) {
    return v > 20.f ? v : log1pf(expf(v));
}
__device__ __forceinline__ u16 f2bf(float f) {
    union { float f; unsigned u; } x; x.f = f;
    return (u16)((x.u + 0x7fffu + ((x.u >> 16) & 1u)) >> 16);
}
__device__ __forceinline__ float bf2f(u16 v) {
    union { unsigned u; float f; } x; x.u = ((unsigned)v) << 16; return x.f;
}
__device__ __forceinline__ void gl16(const void* g, void* l) {
    __builtin_amdgcn_global_load_lds(
        (const __attribute__((address_space(1))) void*)g,
        (__attribute__((address_space(3))) void*)l, 16, 0, 0);
}

// ---------------------------------------------------------------- gating ----
__global__ void __launch_bounds__(64) gate_kernel(
    const float* __restrict__ X, const float* __restrict__ GW,
    const float* __restrict__ GB, const float* __restrict__ GN,
    float* __restrict__ mask)
{
    const int m = blockIdx.x;
    const int t = threadIdx.x;
    const float* x = X + (size_t)m * DMODEL;
    float s0 = 0.f, s1 = 0.f, s2 = 0.f, s3 = 0.f;
    for (int k = t; k < DMODEL; k += 64) {
        float xv = x[k];
        s0 += xv * GW[k];
        s1 += xv * GW[512 + k];
        s2 += xv * GW[1024 + k];
        s3 += xv * GW[1536 + k];
    }
    #pragma unroll
    for (int o = 32; o > 0; o >>= 1) {
        s0 += __shfl_down(s0, o);
        s1 += __shfl_down(s1, o);
        s2 += __shfl_down(s2, o);
        s3 += __shfl_down(s3, o);
    }
    if (t == 0) {
        float lg[4] = { s0 + GB[0] + GN[m*4+0]*0.01f,
                        s1 + GB[1] + GN[m*4+1]*0.01f,
                        s2 + GB[2] + GN[m*4+2]*0.01f,
                        s3 + GB[3] + GN[m*4+3]*0.01f };
        float mx = fmaxf(fmaxf(lg[0], lg[1]), fmaxf(lg[2], lg[3]));
        float p[4]; float sum = 0.f;
        #pragma unroll
        for (int e = 0; e < 4; ++e) { p[e] = expf(lg[e] - mx); sum += p[e]; }
        #pragma unroll
        for (int e = 0; e < 4; ++e) p[e] /= sum;
        int i0 = 0;
        #pragma unroll
        for (int e = 1; e < 4; ++e) if (p[e] > p[i0]) i0 = e;
        int i1 = -1;
        #pragma unroll
        for (int e = 0; e < 4; ++e) {
            if (e == i0) continue;
            if (i1 < 0 || p[e] > p[i1]) i1 = e;
        }
        float s2v = p[i0] + p[i1];
        #pragma unroll
        for (int e = 0; e < 4; ++e)
            mask[m*4 + e] = (e == i0 || e == i1) ? p[e] / s2v : 0.f;
    }
}

// ------------------------------------------------------- f32 -> bf16 copy ---
__global__ void __launch_bounds__(256) cvt_kernel(
    const float* __restrict__ src, u16* __restrict__ dst, int n8)
{
    const int i = blockIdx.x * 256 + threadIdx.x;
    if (i >= n8) return;
    const float4 a = ((const float4*)src)[i*2];
    const float4 b = ((const float4*)src)[i*2 + 1];
    short8 o;
    o[0]=f2bf(a.x); o[1]=f2bf(a.y); o[2]=f2bf(a.z); o[3]=f2bf(a.w);
    o[4]=f2bf(b.x); o[5]=f2bf(b.y); o[6]=f2bf(b.z); o[7]=f2bf(b.w);
    ((short8*)dst)[i] = o;
}

// ------------------------------------------------- bf16 GEMM (m97-style) ----
// OUT[M x N] = A(bf16, M x K, stride lda) @ B(bf16, N x K row-major)^T
// 128x128 tile, BK=64, 4 waves, global_load_lds staging.
// MODE 0: OUT bf16, row stride ldo. MODE 2: OUT f32 512-stride,
//         out (+)= mask[m*4+e]*acc.
template<int MODE>
__global__ void __launch_bounds__(256) gemm_bb(
    const u16* __restrict__ A, int lda, int Mrows,
    const u16* __restrict__ B, int K,
    void* __restrict__ OUT, int ldo,
    const float* __restrict__ mask, int e, int first)
{
    __shared__ u16 As[128][64];
    __shared__ u16 Bs[128][64];
    const int t  = threadIdx.x;
    const int m0 = blockIdx.y * 128;
    const int n0 = blockIdx.x * 128;
    const int w  = t >> 6, l = t & 63;
    const int wm = (w >> 1) * 64, wn = (w & 1) * 64;
    const int sr = l >> 3;           // 0..7 (row within 8-row chunk)
    const int sc = (l & 7) * 8;      // bf16 col 0..56

    f32x4 acc[4][4];
    #pragma unroll
    for (int i = 0; i < 4; ++i)
        #pragma unroll
        for (int j = 0; j < 4; ++j) {
            acc[i][j][0]=0.f; acc[i][j][1]=0.f; acc[i][j][2]=0.f; acc[i][j][3]=0.f;
        }

    for (int k0 = 0; k0 < K; k0 += 64) {
        #pragma unroll
        for (int c = 0; c < 4; ++c) {
            const int row = w*32 + c*8;      // wave-uniform chunk base row
            int ga = m0 + row + sr; if (ga >= Mrows) ga = Mrows - 1;
            gl16(A + (size_t)ga*lda + k0 + sc, &As[row][0]);
            const int gb = n0 + row + sr;
            gl16(B + (size_t)gb*K + k0 + sc, &Bs[row][0]);
        }
        __syncthreads();
        #pragma unroll
        for (int ks = 0; ks < 2; ++ks) {
            short8 af[4], bf[4];
            const int ko = ks*32 + (l >> 4)*8;
            #pragma unroll
            for (int i = 0; i < 4; ++i) {
                af[i] = *(const short8*)&As[wm + i*16 + (l & 15)][ko];
                bf[i] = *(const short8*)&Bs[wn + i*16 + (l & 15)][ko];
            }
            #pragma unroll
            for (int i = 0; i < 4; ++i)
                #pragma unroll
                for (int j = 0; j < 4; ++j)
                    acc[i][j] = __builtin_amdgcn_mfma_f32_16x16x32_bf16(
                        af[i], bf[j], acc[i][j], 0, 0, 0);
        }
        __syncthreads();
    }

    #pragma unroll
    for (int i = 0; i < 4; ++i) {
        #pragma unroll
        for (int r = 0; r < 4; ++r) {
            const int m = m0 + wm + i*16 + (l >> 4)*4 + r;
            if (m >= Mrows) continue;
            if (MODE == 2) {
                const float wgt = mask[m*4 + e];
                #pragma unroll
                for (int j = 0; j < 4; ++j) {
                    const int n = n0 + wn + j*16 + (l & 15);
                    float* o = (float*)OUT + (size_t)m*512 + n;
                    const float v = wgt * acc[i][j][r];
                    *o = first ? v : *o + v;
                }
            } else {
                #pragma unroll
                for (int j = 0; j < 4; ++j) {
                    const int n = n0 + wn + j*16 + (l & 15);
                    ((u16*)OUT)[(size_t)m*ldo + n] = f2bf(acc[i][j][r]);
                }
            }
        }
    }
}

// ------------------------------------------------------------- dt GEMV f32 --
__global__ void __launch_bounds__(256) dt_kernel(
    const float* __restrict__ X,
    const float* __restrict__ Wd,    // 16 x 512 (dt rows of in_proj, f32)
    const float* __restrict__ dtb,   // 16
    float* __restrict__ DT)          // M x 16
{
    const int m = blockIdx.x;
    const int t = threadIdx.x;
    __shared__ float xs[512];
    xs[t] = X[(size_t)m*DMODEL + t];
    xs[t + 256] = X[(size_t)m*DMODEL + 256 + t];
    __syncthreads();
    const int w = t >> 6, l = t & 63;
    #pragma unroll
    for (int q = 0; q < 4; ++q) {
        const int hh = w*4 + q;
        const float* wr = Wd + (size_t)hh * DMODEL;
        float s = 0.f;
        for (int k = l; k < DMODEL; k += 64) s += xs[k] * wr[k];
        #pragma unroll
        for (int o = 32; o > 0; o >>= 1) s += __shfl_xor(s, o);
        if (l == 0) DT[(size_t)m*NH + hh] = softplusf(s + dtb[hh]);
    }
}

// ---------------------------------------------------- conv4 + SiLU pre-pass -
__global__ void __launch_bounds__(256) conv_kernel(
    const u16* __restrict__ XBC,     // M x 1280 bf16 raw
    u16* __restrict__ XCONV,         // M x 1280 bf16
    const float* __restrict__ conv_w,
    const float* __restrict__ conv_b,
    int eg)
{
    const int cg = blockIdx.x;       // 0..3 col group of 320
    const int lt = blockIdx.y;       // 0..62 row tile of 32
    const int b  = blockIdx.z;
    const int t  = threadIdx.x;
    const int l0 = lt * 32, cbase = cg * 320;

    __shared__ float raw[35][320];
    __shared__ float cw[320][4];
    __shared__ float cb[320];

    for (int idx = t; idx < 35*320; idx += 256) {
        const int r = idx / 320, c = idx - r*320;
        const int l = l0 - 3 + r;
        raw[r][c] = (l >= 0 && l < L_SEQ)
            ? bf2f(XBC[((size_t)b*L_SEQ + l)*CONVD + cbase + c]) : 0.f;
    }
    for (int c = t; c < 320; c += 256) {
        #pragma unroll
        for (int k = 0; k < 4; ++k)
            cw[c][k] = conv_w[((size_t)eg*CONVD + cbase + c)*4 + k];
        cb[c] = conv_b[eg*CONVD + cbase + c];
    }
    __syncthreads();
    for (int idx = t; idx < 32*320; idx += 256) {
        const int ro = idx / 320, c = idx - ro*320;
        const int l = l0 + ro;
        if (l >= L_SEQ) continue;
        float v = raw[ro][c]*cw[c][0] + raw[ro+1][c]*cw[c][1]
                + raw[ro+2][c]*cw[c][2] + raw[ro+3][c]*cw[c][3] + cb[c];
        XCONV[((size_t)b*L_SEQ + l)*CONVD + cbase + c] = f2bf(siluf(v));
    }
}

// --------------------------------------------------- SSD pass 1 (per chunk) -
__global__ void __launch_bounds__(512) ssd1_kernel(
    u16* __restrict__ XCONV,
    const float* __restrict__ DT,
    float* __restrict__ Acum,          // bh x 2000
    u16* __restrict__ Hend,            // (bh*NC+g) x 128 x 64
    float* __restrict__ cbuf,          // bh*NC+g
    const float* __restrict__ A_log,
    const float* __restrict__ Dskip,
    int eg)
{
    const int g = blockIdx.x, h = blockIdx.y, b = blockIdx.z;
    const int t = threadIdx.x;
    const int ln = t & 63, w = t >> 6;
    const int bh = b*NH + h;
    const int l0 = g * TCH;

    __shared__ u16 Bc[TCH][LPAD];
    __shared__ u16 Cc[TCH][LPAD];
    __shared__ u16 Xt[HD][LPAD];
    __shared__ u16 Pb[TCH][LPAD];
    __shared__ float ac[TCH], wj[TCH], dtb[TCH];

    const float Ah = -__expf(A_log[eg*NH + h]);
    const float Dv = Dskip[eg*NH + h];

    {
        const int i = t >> 2, q = t & 3;
        const bool v = (l0 + i) < L_SEQ;
        const u16* src = XCONV + (size_t)(b*L_SEQ + l0 + i) * CONVD;
        const short8 z8 = {0,0,0,0,0,0,0,0};
        #pragma unroll
        for (int u = 0; u < 4; ++u) {
            short8 bv = v ? *(const short8*)(src + 1024 + q*32 + u*8) : z8;
            short8 cv = v ? *(const short8*)(src + 1152 + q*32 + u*8) : z8;
            *(short8*)&Bc[i][q*32 + u*8] = bv;
            *(short8*)&Cc[i][q*32 + u*8] = cv;
        }
        #pragma unroll
        for (int u = 0; u < 2; ++u) {
            short8 xv = v ? *(const short8*)(src + h*HD + q*16 + u*8) : z8;
            #pragma unroll
            for (int k = 0; k < 8; ++k)
                Xt[q*16 + u*8 + k][i] = ((const u16*)&xv)[k];
        }
        if (t < TCH) {
            const int l = l0 + t;
            dtb[t] = (l < L_SEQ) ? DT[(size_t)(b*L_SEQ + l)*NH + h] : 0.f;
        }
    }
    __syncthreads();

    if (w == 0) {
        float s0 = dtb[ln] * Ah;
        float s1 = dtb[64 + ln] * Ah;
        #pragma unroll
        for (int o = 1; o < 64; o <<= 1) {
            float v0 = __shfl_up(s0, o);
            float v1 = __shfl_up(s1, o);
            if (ln >= o) { s0 += v0; s1 += v1; }
        }
        s1 += __shfl(s0, 63);
        const float acT = __shfl(s1, 63);
        ac[ln] = s0; ac[64 + ln] = s1;
        wj[ln]      = __expf(acT - s0) * dtb[ln];
        wj[64 + ln] = __expf(acT - s1) * dtb[64 + ln];
        if (l0 + ln < L_SEQ)      Acum[(size_t)bh*L_SEQ + l0 + ln] = s0;
        if (l0 + 64 + ln < L_SEQ) Acum[(size_t)bh*L_SEQ + l0 + 64 + ln] = s1;
        if (ln == 63) cbuf[bh*NC + g] = __expf(acT);
    }
    __syncthreads();

    // S = Cc @ Bc^T
    f32x4 sacc[8];
    #pragma unroll
    for (int c = 0; c < 8; ++c) { sacc[c][0]=0.f; sacc[c][1]=0.f; sacc[c][2]=0.f; sacc[c][3]=0.f; }
    #pragma unroll
    for (int ks = 0; ks < 4; ++ks) {
        short8 afr = *(const short8*)&Cc[w*16 + (ln & 15)][ks*32 + (ln >> 4)*8];
        #pragma unroll
        for (int ct = 0; ct < 8; ++ct) {
            short8 bfr = *(const short8*)&Bc[ct*16 + (ln & 15)][ks*32 + (ln >> 4)*8];
            sacc[ct] = __builtin_amdgcn_mfma_f32_16x16x32_bf16(afr, bfr, sacc[ct], 0, 0, 0);
        }
    }
    // P = mask * S * exp(ac_i - ac_j) * dt_j
    {
        const int i0 = w*16 + (ln >> 4)*4;
        float aci[4];
        #pragma unroll
        for (int r = 0; r < 4; ++r) aci[r] = ac[i0 + r];
        #pragma unroll
        for (int ct = 0; ct < 8; ++ct) {
            const int j = ct*16 + (ln & 15);
            const float acj = ac[j], dtj = dtb[j];
            #pragma unroll
            for (int r = 0; r < 4; ++r) {
                const int i2 = i0 + r;
                float pv = (j <= i2) ? sacc[ct][r] * __expf(aci[r] - acj) * dtj : 0.f;
                Pb[i2][j] = f2bf(pv);
            }
        }
    }
    __syncthreads();

    // Y1 = P @ X (+ D*x)
    {
        f32x4 yacc[4];
        #pragma unroll
        for (int p = 0; p < 4; ++p) { yacc[p][0]=0.f; yacc[p][1]=0.f; yacc[p][2]=0.f; yacc[p][3]=0.f; }
        #pragma unroll
        for (int ks = 0; ks < 4; ++ks) {
            short8 afr = *(const short8*)&Pb[w*16 + (ln & 15)][ks*32 + (ln >> 4)*8];
            #pragma unroll
            for (int pt = 0; pt < 4; ++pt) {
                short8 bfr = *(const short8*)&Xt[pt*16 + (ln & 15)][ks*32 + (ln >> 4)*8];
                yacc[pt] = __builtin_amdgcn_mfma_f32_16x16x32_bf16(afr, bfr, yacc[pt], 0, 0, 0);
            }
        }
        #pragma unroll
        for (int pt = 0; pt < 4; ++pt) {
            const int p = pt*16 + (ln & 15);
            #pragma unroll
            for (int r = 0; r < 4; ++r) {
                const int i2 = w*16 + (ln >> 4)*4 + r;
                const int lg = l0 + i2;
                if (lg < L_SEQ) {
                    const float xv = bf2f(Xt[p][i2]);
                    XCONV[(size_t)(b*L_SEQ + lg)*CONVD + h*HD + p] =
                        f2bf(yacc[pt][r] + Dv * xv);
                }
            }
        }
    }

    // Hloc = (Bc^T * wj) @ X
    {
        f32x4 hacc[4];
        #pragma unroll
        for (int p = 0; p < 4; ++p) { hacc[p][0]=0.f; hacc[p][1]=0.f; hacc[p][2]=0.f; hacc[p][3]=0.f; }
        #pragma unroll
        for (int ks = 0; ks < 4; ++ks) {
            const int jb = ks*32 + (ln >> 4)*8;
            const int nr = w*16 + (ln & 15);
            short8 afr;
            #pragma unroll
            for (int jj = 0; jj < 8; ++jj)
                afr[jj] = (short)f2bf(bf2f(Bc[jb + jj][nr]) * wj[jb + jj]);
            #pragma unroll
            for (int pt = 0; pt < 4; ++pt) {
                short8 bfr = *(const short8*)&Xt[pt*16 + (ln & 15)][jb];
                hacc[pt] = __builtin_amdgcn_mfma_f32_16x16x32_bf16(afr, bfr, hacc[pt], 0, 0, 0);
            }
        }
        u16* Hb = Hend + (size_t)(bh*NC + g) * (TCH*HD);
        #pragma unroll
        for (int pt = 0; pt < 4; ++pt)
            #pragma unroll
            for (int r = 0; r < 4; ++r) {
                const int n = w*16 + (ln >> 4)*4 + r;
                Hb[n*HD + pt*16 + (ln & 15)] = f2bf(hacc[pt][r]);
            }
    }
}

// --------------------------------------- pass 2: chunk-state propagation ----
__global__ void __launch_bounds__(256) prop_kernel(
    u16* __restrict__ Hend, const float* __restrict__ cbuf)
{
    const int bh = blockIdx.x;
    const int t  = threadIdx.x;
    float hs[32];
    #pragma unroll
    for (int j = 0; j < 32; ++j) hs[j] = 0.f;
    for (int g = 0; g < NC - 1; ++g) {
        const float ce = cbuf[bh*NC + g];
        u16* He = Hend + (size_t)(bh*NC + g)*(TCH*HD) + t*32;
        #pragma unroll
        for (int j = 0; j < 32; ++j) {
            const float lo = bf2f(He[j]);
            hs[j] = ce*hs[j] + lo;
            He[j] = f2bf(hs[j]);
        }
    }
}

// --------------------------------------------- pass 3: Y2 = Cs @ h_start ----
__global__ void __launch_bounds__(256) ssd2_kernel(
    u16* __restrict__ XCONV,
    const float* __restrict__ Acum,
    const u16* __restrict__ Hend)
{
    const int g = blockIdx.x, h = blockIdx.y, b = blockIdx.z;
    if (g == 0) return;
    const int t = threadIdx.x, ln = t & 63, w = t >> 6;
    const int bh = b*NH + h;
    const int l0 = g * TCH;

    __shared__ u16 Cs[TCH][LPAD];
    __shared__ u16 Ht[HD][LPAD];

    {
        const int i = t >> 1, q = t & 1;
        const bool v = (l0 + i) < L_SEQ;
        const float eaci = v ? __expf(Acum[(size_t)bh*L_SEQ + l0 + i]) : 0.f;
        const u16* src = XCONV + (size_t)(b*L_SEQ + l0 + i)*CONVD + 1152 + q*64;
        const short8 z8 = {0,0,0,0,0,0,0,0};
        #pragma unroll
        for (int u = 0; u < 8; ++u) {
            short8 cv = v ? *(const short8*)(src + u*8) : z8;
            short8 ov;
            #pragma unroll
            for (int k = 0; k < 8; ++k)
                ov[k] = (short)f2bf(bf2f(((const u16*)&cv)[k]) * eaci);
            *(short8*)&Cs[i][q*64 + u*8] = ov;
        }
    }
    {
        const u16* Hb = Hend + (size_t)(bh*NC + g - 1)*(TCH*HD) + t*32;
        #pragma unroll
        for (int k = 0; k < 32; ++k) {
            const int idx = t*32 + k;
            Ht[idx & 63][idx >> 6] = Hb[k];
        }
    }
    __syncthreads();

    f32x4 acc2[2][4];
    #pragma unroll
    for (int rt = 0; rt < 2; ++rt)
        #pragma unroll
        for (int pt = 0; pt < 4; ++pt) { acc2[rt][pt][0]=0.f; acc2[rt][pt][1]=0.f; acc2[rt][pt][2]=0.f; acc2[rt][pt][3]=0.f; }
    #pragma unroll
    for (int ks = 0; ks < 4; ++ks) {
        short8 af0 = *(const short8*)&Cs[w*32 +      (ln & 15)][ks*32 + (ln >> 4)*8];
        short8 af1 = *(const short8*)&Cs[w*32 + 16 + (ln & 15)][ks*32 + (ln >> 4)*8];
        #pragma unroll
        for (int pt = 0; pt < 4; ++pt) {
            short8 bfr = *(const short8*)&Ht[pt*16 + (ln & 15)][ks*32 + (ln >> 4)*8];
            acc2[0][pt] = __builtin_amdgcn_mfma_f32_16x16x32_bf16(af0, bfr, acc2[0][pt], 0, 0, 0);
            acc2[1][pt] = __builtin_amdgcn_mfma_f32_16x16x32_bf16(af1, bfr, acc2[1][pt], 0, 0, 0);
        }
    }
    #pragma unroll
    for (int rt = 0; rt < 2; ++rt)
        #pragma unroll
        for (int pt = 0; pt < 4; ++pt)
            #pragma unroll
            for (int r = 0; r < 4; ++r) {
                const int i2 = w*32 + rt*16 + (ln >> 4)*4 + r;
                const int lg = l0 + i2;
                if (lg < L_SEQ) {
                    u16* yp = XCONV + (size_t)(b*L_SEQ + lg)*CONVD + h*HD + pt*16 + (ln & 15);
                    *yp = f2bf(bf2f(*yp) + acc2[rt][pt][r]);
                }
            }
}

// ------------------------------------------------- gated RMS norm (bf16) ----
__global__ void __launch_bounds__(256) norm_kernel(
    u16* __restrict__ Ybuf,            // rows, stride 1280 (bf16), in-place
    const u16* __restrict__ Z,         // rows x 1024 bf16
    const float* __restrict__ nw)      // 1024
{
    const int row = blockIdx.x;
    const int t = threadIdx.x;
    u16* y = Ybuf + (size_t)row * CONVD;
    const u16* z = Z + (size_t)row * DINNER;

    ushort4 yv = *(const ushort4*)(y + t*4);
    ushort4 zv = *(const ushort4*)(z + t*4);
    float v[4]; float ss = 0.f;
    #pragma unroll
    for (int j = 0; j < 4; ++j) {
        const float zz = bf2f(((const u16*)&zv)[j]);
        const float vv = bf2f(((const u16*)&yv)[j]) * siluf(zz);
        v[j] = vv; ss += vv*vv;
    }
    #pragma unroll
    for (int o = 32; o > 0; o >>= 1) ss += __shfl_down(ss, o);
    __shared__ float wsum[4];
    if ((t & 63) == 0) wsum[t >> 6] = ss;
    __syncthreads();
    const float total = wsum[0] + wsum[1] + wsum[2] + wsum[3];
    const float scale = rsqrtf(total / (float)DINNER + 1e-5f);
    ushort4 ov;
    #pragma unroll
    for (int j = 0; j < 4; ++j)
        ((u16*)&ov)[j] = f2bf(v[j] * scale * nw[t*4 + j]);
    *(ushort4*)(y + t*4) = ov;
}

// ------------------------------------------------------------------ host ----
extern "C" void kernel_launch(void* const* d_in, const int* in_sizes, int n_in,
                              void* d_out, int out_size, void* d_ws, size_t ws_size,
                              hipStream_t stream)
{
    const float* x        = (const float*)d_in[0];
    const float* gate_w   = (const float*)d_in[1];
    const float* gate_b   = (const float*)d_in[2];
    const float* gate_n   = (const float*)d_in[3];
    const float* in_w     = (const float*)d_in[4];
    const float* conv_w   = (const float*)d_in[5];
    const float* conv_b   = (const float*)d_in[6];
    const float* dt_bias  = (const float*)d_in[7];
    const float* A_log    = (const float*)d_in[8];
    const float* Dskip    = (const float*)d_in[9];
    const float* norm_w   = (const float*)d_in[10];
    const float* out_w    = (const float*)d_in[11];
    float* out = (float*)d_out;

    char* ws = (char*)d_ws;
    // R1 serves sequentially: XBCraw bf16 (gemm->conv) -> Hend (ssd1->ssd2)
    //                         -> Ztile bf16 full-M (z-gemm->norm)
    u16*   R1     = (u16*)ws;                        // 20,480,000 B
    u16*   XCONV  = (u16*)(ws + 20480000);           // 20,480,000 B
    u16*   xbf    = (u16*)(ws + 40960000);           //  8,192,000 B
    u16*   inwb   = (u16*)(ws + 49152000);           //  9,437,184 B
    u16*   outwb  = (u16*)(ws + 58589184);           //  4,194,304 B
    float* DTb    = (float*)(ws + 62783488);         //    512,000 B
    float* Acum   = (float*)(ws + 63295488);         //    512,000 B
    float* cbuf   = (float*)(ws + 63807488);         //      4,096 B
    float* maskb  = (float*)(ws + 63811584);         //    128,000 B
    // total 63,939,584 B (< 74.36 MB proven-safe)

    gate_kernel<<<M_TOK, 64, 0, stream>>>(x, gate_w, gate_b, gate_n, maskb);
    // one-time bf16 conversions
    cvt_kernel<<<2000, 256, 0, stream>>>(x, xbf, 512000);
    for (int e = 0; e < NEXP; ++e)
        cvt_kernel<<<576, 256, 0, stream>>>(
            in_w + (size_t)e*DIN_ALL*DMODEL, inwb + (size_t)e*2304*512, 147456);
    cvt_kernel<<<1024, 256, 0, stream>>>(out_w, outwb, 262144);

    for (int e = 0; e < NEXP; ++e) {
        const u16* Wxbc = inwb + (size_t)e*2304*512 + (size_t)1024*512;
        const u16* Wz   = inwb + (size_t)e*2304*512;
        // raw xBC (bf16): grid 10 x 63
        gemm_bb<0><<<dim3(10, 63), 256, 0, stream>>>(
            xbf, DMODEL, M_TOK, Wxbc, DMODEL, R1, CONVD, nullptr, 0, 0);
        dt_kernel<<<M_TOK, 256, 0, stream>>>(
            x, in_w + (size_t)e*DIN_ALL*DMODEL + (size_t)2304*DMODEL,
            dt_bias + e*NH, DTb);
        conv_kernel<<<dim3(4, 63, BATCH), 256, 0, stream>>>(
            R1, XCONV, conv_w, conv_b, e);
        ssd1_kernel<<<dim3(NC, NH, BATCH), 512, 0, stream>>>(
            XCONV, DTb, Acum, (u16*)R1, cbuf, A_log, Dskip, e);
        prop_kernel<<<BATCH*NH, 256, 0, stream>>>((u16*)R1, cbuf);
        ssd2_kernel<<<dim3(NC, NH, BATCH), 256, 0, stream>>>(
            XCONV, Acum, (const u16*)R1);
        // z (bf16, full M) into R1 (Hend now dead)
        gemm_bb<0><<<dim3(8, 63), 256, 0, stream>>>(
            xbf, DMODEL, M_TOK, Wz, DMODEL, R1, DINNER, nullptr, 0, 0);
        norm_kernel<<<M_TOK, 256, 0, stream>>>(
            XCONV, R1, norm_w + (size_t)e*DINNER);
        gemm_bb<2><<<dim3(4, 63), 256, 0, stream>>>(
            XCONV, CONVD, M_TOK, outwb + (size_t)e*DMODEL*DINNER, DINNER,
            out, 512, maskb, e, e == 0 ? 1 : 0);
    }
}

// Round 7
// 975.080 us; speedup vs baseline: 9.2514x; 1.1201x over previous
//
#include <hip/hip_runtime.h>
#include <hip/hip_bf16.h>

#define M_TOK   8000
#define L_SEQ   2000
#define BATCH   4
#define NEXP    4
#define NH      16
#define HD      64
#define DSTATE  128
#define DMODEL  512
#define DINNER  1024
#define CONVD   1280
#define DIN_ALL 2320   // 1024 z + 1280 xBC + 16 dt
#define TCH     128    // SSD chunk length
#define NC      16     // chunks per sequence
#define LPAD    136    // LDS row pitch (shorts) for SSD tiles

typedef __attribute__((ext_vector_type(8))) short short8;
typedef __attribute__((ext_vector_type(4))) float f32x4;
typedef unsigned short u16;

__device__ __forceinline__ float siluf(float v) {
    return v / (1.f + __expf(-v));
}
__device__ __forceinline__ float softplusf(float v) {
    return v > 20.f ? v : log1pf(expf(v));
}
__device__ __forceinline__ u16 f2bf(float f) {
    union { float f; unsigned u; } x; x.f = f;
    return (u16)((x.u + 0x7fffu + ((x.u >> 16) & 1u)) >> 16);
}
__device__ __forceinline__ float bf2f(u16 v) {
    union { unsigned u; float f; } x; x.u = ((unsigned)v) << 16; return x.f;
}
__device__ __forceinline__ void gl16(const void* g, void* l) {
    __builtin_amdgcn_global_load_lds(
        (const __attribute__((address_space(1))) void*)g,
        (__attribute__((address_space(3))) void*)l, 16, 0, 0);
}

// ---------------------------------------------------------------- gating ----
__global__ void __launch_bounds__(64) gate_kernel(
    const float* __restrict__ X, const float* __restrict__ GW,
    const float* __restrict__ GB, const float* __restrict__ GN,
    float* __restrict__ mask)
{
    const int m = blockIdx.x;
    const int t = threadIdx.x;
    const float* x = X + (size_t)m * DMODEL;
    float s0 = 0.f, s1 = 0.f, s2 = 0.f, s3 = 0.f;
    for (int k = t; k < DMODEL; k += 64) {
        float xv = x[k];
        s0 += xv * GW[k];
        s1 += xv * GW[512 + k];
        s2 += xv * GW[1024 + k];
        s3 += xv * GW[1536 + k];
    }
    #pragma unroll
    for (int o = 32; o > 0; o >>= 1) {
        s0 += __shfl_down(s0, o);
        s1 += __shfl_down(s1, o);
        s2 += __shfl_down(s2, o);
        s3 += __shfl_down(s3, o);
    }
    if (t == 0) {
        float lg[4] = { s0 + GB[0] + GN[m*4+0]*0.01f,
                        s1 + GB[1] + GN[m*4+1]*0.01f,
                        s2 + GB[2] + GN[m*4+2]*0.01f,
                        s3 + GB[3] + GN[m*4+3]*0.01f };
        float mx = fmaxf(fmaxf(lg[0], lg[1]), fmaxf(lg[2], lg[3]));
        float p[4]; float sum = 0.f;
        #pragma unroll
        for (int e = 0; e < 4; ++e) { p[e] = expf(lg[e] - mx); sum += p[e]; }
        #pragma unroll
        for (int e = 0; e < 4; ++e) p[e] /= sum;
        int i0 = 0;
        #pragma unroll
        for (int e = 1; e < 4; ++e) if (p[e] > p[i0]) i0 = e;
        int i1 = -1;
        #pragma unroll
        for (int e = 0; e < 4; ++e) {
            if (e == i0) continue;
            if (i1 < 0 || p[e] > p[i1]) i1 = e;
        }
        float s2v = p[i0] + p[i1];
        #pragma unroll
        for (int e = 0; e < 4; ++e)
            mask[m*4 + e] = (e == i0 || e == i1) ? p[e] / s2v : 0.f;
    }
}

// ------------------------------------------------------- f32 -> bf16 copy ---
__global__ void __launch_bounds__(256) cvt_kernel(
    const float* __restrict__ src, u16* __restrict__ dst, int n8)
{
    const int i = blockIdx.x * 256 + threadIdx.x;
    if (i >= n8) return;
    const float4 a = ((const float4*)src)[i*2];
    const float4 b = ((const float4*)src)[i*2 + 1];
    short8 o;
    o[0]=f2bf(a.x); o[1]=f2bf(a.y); o[2]=f2bf(a.z); o[3]=f2bf(a.w);
    o[4]=f2bf(b.x); o[5]=f2bf(b.y); o[6]=f2bf(b.z); o[7]=f2bf(b.w);
    ((short8*)dst)[i] = o;
}
__global__ void __launch_bounds__(256) zero_kernel(u16* __restrict__ dst, int n8)
{
    const int i = blockIdx.x * 256 + threadIdx.x;
    if (i >= n8) return;
    const short8 z8 = {0,0,0,0,0,0,0,0};
    ((short8*)dst)[i] = z8;
}

// ------------------------------------------------- bf16 GEMM (m97-style) ----
// OUT[M x N] = A(bf16, M x K, stride lda) @ B(bf16, N x K row-major)^T
// 128x128 tile, BK=64, 4 waves, global_load_lds staging.
// MODE 0: OUT bf16, row stride ldo.
// MODE 2: OUT f32 512-stride, out (+)= mask[m*4+e]*acc.
// MODE 3: OUT f32 DT (stride 16, n<16): softplus(acc + dtb[n]); mask=dtb.
template<int MODE>
__global__ void __launch_bounds__(256) gemm_bb(
    const u16* __restrict__ A, int lda, int Mrows,
    const u16* __restrict__ B, int K,
    void* __restrict__ OUT, int ldo,
    const float* __restrict__ mask, int e, int first)
{
    __shared__ u16 As[128][64];
    __shared__ u16 Bs[128][64];
    const int t  = threadIdx.x;
    const int m0 = blockIdx.y * 128;
    const int n0 = blockIdx.x * 128;
    const int w  = t >> 6, l = t & 63;
    const int wm = (w >> 1) * 64, wn = (w & 1) * 64;
    const int sr = l >> 3;           // 0..7 (row within 8-row chunk)
    const int sc = (l & 7) * 8;      // bf16 col 0..56

    f32x4 acc[4][4];
    #pragma unroll
    for (int i = 0; i < 4; ++i)
        #pragma unroll
        for (int j = 0; j < 4; ++j) {
            acc[i][j][0]=0.f; acc[i][j][1]=0.f; acc[i][j][2]=0.f; acc[i][j][3]=0.f;
        }

    for (int k0 = 0; k0 < K; k0 += 64) {
        #pragma unroll
        for (int c = 0; c < 4; ++c) {
            const int row = w*32 + c*8;      // wave-uniform chunk base row
            int ga = m0 + row + sr; if (ga >= Mrows) ga = Mrows - 1;
            gl16(A + (size_t)ga*lda + k0 + sc, &As[row][0]);
            const int gb = n0 + row + sr;
            gl16(B + (size_t)gb*K + k0 + sc, &Bs[row][0]);
        }
        __syncthreads();
        #pragma unroll
        for (int ks = 0; ks < 2; ++ks) {
            short8 af[4], bf[4];
            const int ko = ks*32 + (l >> 4)*8;
            #pragma unroll
            for (int i = 0; i < 4; ++i) {
                af[i] = *(const short8*)&As[wm + i*16 + (l & 15)][ko];
                bf[i] = *(const short8*)&Bs[wn + i*16 + (l & 15)][ko];
            }
            #pragma unroll
            for (int i = 0; i < 4; ++i)
                #pragma unroll
                for (int j = 0; j < 4; ++j)
                    acc[i][j] = __builtin_amdgcn_mfma_f32_16x16x32_bf16(
                        af[i], bf[j], acc[i][j], 0, 0, 0);
        }
        __syncthreads();
    }

    #pragma unroll
    for (int i = 0; i < 4; ++i) {
        #pragma unroll
        for (int r = 0; r < 4; ++r) {
            const int m = m0 + wm + i*16 + (l >> 4)*4 + r;
            if (m >= Mrows) continue;
            if (MODE == 2) {
                const float wgt = mask[m*4 + e];
                #pragma unroll
                for (int j = 0; j < 4; ++j) {
                    const int n = n0 + wn + j*16 + (l & 15);
                    float* o = (float*)OUT + (size_t)m*512 + n;
                    const float v = wgt * acc[i][j][r];
                    *o = first ? v : *o + v;
                }
            } else if (MODE == 3) {
                #pragma unroll
                for (int j = 0; j < 4; ++j) {
                    const int n = n0 + wn + j*16 + (l & 15);
                    if (n < NH)
                        ((float*)OUT)[(size_t)m*NH + n] =
                            softplusf(acc[i][j][r] + mask[n]);
                }
            } else {
                #pragma unroll
                for (int j = 0; j < 4; ++j) {
                    const int n = n0 + wn + j*16 + (l & 15);
                    ((u16*)OUT)[(size_t)m*ldo + n] = f2bf(acc[i][j][r]);
                }
            }
        }
    }
}

// ---------------------------------------- conv4 + SiLU, direct (no LDS) -----
// one thread = 8 channels x 1 row.
__global__ void __launch_bounds__(256) conv_kernel(
    const u16* __restrict__ XBC,     // M x 1280 bf16 raw
    u16* __restrict__ XCONV,         // M x 1280 bf16
    const float* __restrict__ conv_w,
    const float* __restrict__ conv_b,
    int eg)
{
    const int idx = blockIdx.x * 256 + threadIdx.x;
    const int NCG = CONVD / 8;                  // 160
    if (idx >= M_TOK * NCG) return;
    const int cg = idx % NCG;
    const int m  = idx / NCG;
    const int b  = m / L_SEQ, l = m - b*L_SEQ;
    const int c0 = cg * 8;

    const u16* base = XBC + (size_t)b*L_SEQ*CONVD + c0;
    const short8 z8 = {0,0,0,0,0,0,0,0};
    short8 r[4];
    #pragma unroll
    for (int k = 0; k < 4; ++k) {
        const int row = l - 3 + k;
        r[k] = (row >= 0) ? *(const short8*)(base + (size_t)row*CONVD) : z8;
    }
    const float4* wp = (const float4*)(conv_w + ((size_t)eg*CONVD + c0)*4);
    const float*  bp = conv_b + (size_t)eg*CONVD + c0;
    short8 o;
    #pragma unroll
    for (int j = 0; j < 8; ++j) {
        const float4 wj = wp[j];
        float v = bf2f(r[0][j])*wj.x + bf2f(r[1][j])*wj.y
                + bf2f(r[2][j])*wj.z + bf2f(r[3][j])*wj.w + bp[j];
        o[j] = f2bf(siluf(v));
    }
    *(short8*)(XCONV + (size_t)m*CONVD + c0) = o;
}

// --------------------------------------------------- SSD pass 1 (per chunk) -
__global__ void __launch_bounds__(512) ssd1_kernel(
    u16* __restrict__ XCONV,
    const float* __restrict__ DT,
    float* __restrict__ Acum,          // bh x 2000
    u16* __restrict__ Hend,            // (bh*NC+g) x 128 x 64
    float* __restrict__ cbuf,          // bh*NC+g
    const float* __restrict__ A_log,
    const float* __restrict__ Dskip,
    int eg)
{
    const int g = blockIdx.x, h = blockIdx.y, b = blockIdx.z;
    const int t = threadIdx.x;
    const int ln = t & 63, w = t >> 6;
    const int bh = b*NH + h;
    const int l0 = g * TCH;

    __shared__ u16 Bc[TCH][LPAD];
    __shared__ u16 Cc[TCH][LPAD];
    __shared__ u16 Xt[HD][LPAD];
    __shared__ u16 Pb[TCH][LPAD];
    __shared__ float ac[TCH], wj[TCH], dtb[TCH];

    const float Ah = -__expf(A_log[eg*NH + h]);
    const float Dv = Dskip[eg*NH + h];

    {
        const int i = t >> 2, q = t & 3;
        const bool v = (l0 + i) < L_SEQ;
        const u16* src = XCONV + (size_t)(b*L_SEQ + l0 + i) * CONVD;
        const short8 z8 = {0,0,0,0,0,0,0,0};
        #pragma unroll
        for (int u = 0; u < 4; ++u) {
            short8 bv = v ? *(const short8*)(src + 1024 + q*32 + u*8) : z8;
            short8 cv = v ? *(const short8*)(src + 1152 + q*32 + u*8) : z8;
            *(short8*)&Bc[i][q*32 + u*8] = bv;
            *(short8*)&Cc[i][q*32 + u*8] = cv;
        }
        #pragma unroll
        for (int u = 0; u < 2; ++u) {
            short8 xv = v ? *(const short8*)(src + h*HD + q*16 + u*8) : z8;
            #pragma unroll
            for (int k = 0; k < 8; ++k)
                Xt[q*16 + u*8 + k][i] = ((const u16*)&xv)[k];
        }
        if (t < TCH) {
            const int l = l0 + t;
            dtb[t] = (l < L_SEQ) ? DT[(size_t)(b*L_SEQ + l)*NH + h] : 0.f;
        }
    }
    __syncthreads();

    if (w == 0) {
        float s0 = dtb[ln] * Ah;
        float s1 = dtb[64 + ln] * Ah;
        #pragma unroll
        for (int o = 1; o < 64; o <<= 1) {
            float v0 = __shfl_up(s0, o);
            float v1 = __shfl_up(s1, o);
            if (ln >= o) { s0 += v0; s1 += v1; }
        }
        s1 += __shfl(s0, 63);
        const float acT = __shfl(s1, 63);
        ac[ln] = s0; ac[64 + ln] = s1;
        wj[ln]      = __expf(acT - s0) * dtb[ln];
        wj[64 + ln] = __expf(acT - s1) * dtb[64 + ln];
        if (l0 + ln < L_SEQ)      Acum[(size_t)bh*L_SEQ + l0 + ln] = s0;
        if (l0 + 64 + ln < L_SEQ) Acum[(size_t)bh*L_SEQ + l0 + 64 + ln] = s1;
        if (ln == 63) cbuf[bh*NC + g] = __expf(acT);
    }
    __syncthreads();

    // S = Cc @ Bc^T
    f32x4 sacc[8];
    #pragma unroll
    for (int c = 0; c < 8; ++c) { sacc[c][0]=0.f; sacc[c][1]=0.f; sacc[c][2]=0.f; sacc[c][3]=0.f; }
    #pragma unroll
    for (int ks = 0; ks < 4; ++ks) {
        short8 afr = *(const short8*)&Cc[w*16 + (ln & 15)][ks*32 + (ln >> 4)*8];
        #pragma unroll
        for (int ct = 0; ct < 8; ++ct) {
            short8 bfr = *(const short8*)&Bc[ct*16 + (ln & 15)][ks*32 + (ln >> 4)*8];
            sacc[ct] = __builtin_amdgcn_mfma_f32_16x16x32_bf16(afr, bfr, sacc[ct], 0, 0, 0);
        }
    }
    // P = mask * S * exp(ac_i - ac_j) * dt_j
    {
        const int i0 = w*16 + (ln >> 4)*4;
        float aci[4];
        #pragma unroll
        for (int r = 0; r < 4; ++r) aci[r] = ac[i0 + r];
        #pragma unroll
        for (int ct = 0; ct < 8; ++ct) {
            const int j = ct*16 + (ln & 15);
            const float acj = ac[j], dtj = dtb[j];
            #pragma unroll
            for (int r = 0; r < 4; ++r) {
                const int i2 = i0 + r;
                float pv = (j <= i2) ? sacc[ct][r] * __expf(aci[r] - acj) * dtj : 0.f;
                Pb[i2][j] = f2bf(pv);
            }
        }
    }
    __syncthreads();

    // Y1 = P @ X (+ D*x)
    {
        f32x4 yacc[4];
        #pragma unroll
        for (int p = 0; p < 4; ++p) { yacc[p][0]=0.f; yacc[p][1]=0.f; yacc[p][2]=0.f; yacc[p][3]=0.f; }
        #pragma unroll
        for (int ks = 0; ks < 4; ++ks) {
            short8 afr = *(const short8*)&Pb[w*16 + (ln & 15)][ks*32 + (ln >> 4)*8];
            #pragma unroll
            for (int pt = 0; pt < 4; ++pt) {
                short8 bfr = *(const short8*)&Xt[pt*16 + (ln & 15)][ks*32 + (ln >> 4)*8];
                yacc[pt] = __builtin_amdgcn_mfma_f32_16x16x32_bf16(afr, bfr, yacc[pt], 0, 0, 0);
            }
        }
        #pragma unroll
        for (int pt = 0; pt < 4; ++pt) {
            const int p = pt*16 + (ln & 15);
            #pragma unroll
            for (int r = 0; r < 4; ++r) {
                const int i2 = w*16 + (ln >> 4)*4 + r;
                const int lg = l0 + i2;
                if (lg < L_SEQ) {
                    const float xv = bf2f(Xt[p][i2]);
                    XCONV[(size_t)(b*L_SEQ + lg)*CONVD + h*HD + p] =
                        f2bf(yacc[pt][r] + Dv * xv);
                }
            }
        }
    }

    // Hloc = (Bc^T * wj) @ X
    {
        f32x4 hacc[4];
        #pragma unroll
        for (int p = 0; p < 4; ++p) { hacc[p][0]=0.f; hacc[p][1]=0.f; hacc[p][2]=0.f; hacc[p][3]=0.f; }
        #pragma unroll
        for (int ks = 0; ks < 4; ++ks) {
            const int jb = ks*32 + (ln >> 4)*8;
            const int nr = w*16 + (ln & 15);
            short8 afr;
            #pragma unroll
            for (int jj = 0; jj < 8; ++jj)
                afr[jj] = (short)f2bf(bf2f(Bc[jb + jj][nr]) * wj[jb + jj]);
            #pragma unroll
            for (int pt = 0; pt < 4; ++pt) {
                short8 bfr = *(const short8*)&Xt[pt*16 + (ln & 15)][jb];
                hacc[pt] = __builtin_amdgcn_mfma_f32_16x16x32_bf16(afr, bfr, hacc[pt], 0, 0, 0);
            }
        }
        u16* Hb = Hend + (size_t)(bh*NC + g) * (TCH*HD);
        #pragma unroll
        for (int pt = 0; pt < 4; ++pt)
            #pragma unroll
            for (int r = 0; r < 4; ++r) {
                const int n = w*16 + (ln >> 4)*4 + r;
                Hb[n*HD + pt*16 + (ln & 15)] = f2bf(hacc[pt][r]);
            }
    }
}

// --------------------------------------- pass 2: chunk-state propagation ----
__global__ void __launch_bounds__(256) prop_kernel(
    u16* __restrict__ Hend, const float* __restrict__ cbuf)
{
    const int bh = blockIdx.x;
    const int t  = threadIdx.x;
    float hs[32];
    #pragma unroll
    for (int j = 0; j < 32; ++j) hs[j] = 0.f;
    for (int g = 0; g < NC - 1; ++g) {
        const float ce = cbuf[bh*NC + g];
        u16* He = Hend + (size_t)(bh*NC + g)*(TCH*HD) + t*32;
        #pragma unroll
        for (int j = 0; j < 32; ++j) {
            const float lo = bf2f(He[j]);
            hs[j] = ce*hs[j] + lo;
            He[j] = f2bf(hs[j]);
        }
    }
}

// --------------------------------------------- pass 3: Y2 = Cs @ h_start ----
__global__ void __launch_bounds__(256) ssd2_kernel(
    u16* __restrict__ XCONV,
    const float* __restrict__ Acum,
    const u16* __restrict__ Hend)
{
    const int g = blockIdx.x, h = blockIdx.y, b = blockIdx.z;
    if (g == 0) return;
    const int t = threadIdx.x, ln = t & 63, w = t >> 6;
    const int bh = b*NH + h;
    const int l0 = g * TCH;

    __shared__ u16 Cs[TCH][LPAD];
    __shared__ u16 Ht[HD][LPAD];

    {
        const int i = t >> 1, q = t & 1;
        const bool v = (l0 + i) < L_SEQ;
        const float eaci = v ? __expf(Acum[(size_t)bh*L_SEQ + l0 + i]) : 0.f;
        const u16* src = XCONV + (size_t)(b*L_SEQ + l0 + i)*CONVD + 1152 + q*64;
        const short8 z8 = {0,0,0,0,0,0,0,0};
        #pragma unroll
        for (int u = 0; u < 8; ++u) {
            short8 cv = v ? *(const short8*)(src + u*8) : z8;
            short8 ov;
            #pragma unroll
            for (int k = 0; k < 8; ++k)
                ov[k] = (short)f2bf(bf2f(((const u16*)&cv)[k]) * eaci);
            *(short8*)&Cs[i][q*64 + u*8] = ov;
        }
    }
    {
        const u16* Hb = Hend + (size_t)(bh*NC + g - 1)*(TCH*HD) + t*32;
        #pragma unroll
        for (int k = 0; k < 32; ++k) {
            const int idx = t*32 + k;
            Ht[idx & 63][idx >> 6] = Hb[k];
        }
    }
    __syncthreads();

    f32x4 acc2[2][4];
    #pragma unroll
    for (int rt = 0; rt < 2; ++rt)
        #pragma unroll
        for (int pt = 0; pt < 4; ++pt) { acc2[rt][pt][0]=0.f; acc2[rt][pt][1]=0.f; acc2[rt][pt][2]=0.f; acc2[rt][pt][3]=0.f; }
    #pragma unroll
    for (int ks = 0; ks < 4; ++ks) {
        short8 af0 = *(const short8*)&Cs[w*32 +      (ln & 15)][ks*32 + (ln >> 4)*8];
        short8 af1 = *(const short8*)&Cs[w*32 + 16 + (ln & 15)][ks*32 + (ln >> 4)*8];
        #pragma unroll
        for (int pt = 0; pt < 4; ++pt) {
            short8 bfr = *(const short8*)&Ht[pt*16 + (ln & 15)][ks*32 + (ln >> 4)*8];
            acc2[0][pt] = __builtin_amdgcn_mfma_f32_16x16x32_bf16(af0, bfr, acc2[0][pt], 0, 0, 0);
            acc2[1][pt] = __builtin_amdgcn_mfma_f32_16x16x32_bf16(af1, bfr, acc2[1][pt], 0, 0, 0);
        }
    }
    #pragma unroll
    for (int rt = 0; rt < 2; ++rt)
        #pragma unroll
        for (int pt = 0; pt < 4; ++pt)
            #pragma unroll
            for (int r = 0; r < 4; ++r) {
                const int i2 = w*32 + rt*16 + (ln >> 4)*4 + r;
                const int lg = l0 + i2;
                if (lg < L_SEQ) {
                    u16* yp = XCONV + (size_t)(b*L_SEQ + lg)*CONVD + h*HD + pt*16 + (ln & 15);
                    *yp = f2bf(bf2f(*yp) + acc2[rt][pt][r]);
                }
            }
}

// ------------------------------------------------- gated RMS norm (bf16) ----
__global__ void __launch_bounds__(256) norm_kernel(
    u16* __restrict__ Ybuf,            // rows, stride 1280 (bf16), in-place
    const u16* __restrict__ Z,         // rows x 1024 bf16
    const float* __restrict__ nw)      // 1024
{
    const int row = blockIdx.x;
    const int t = threadIdx.x;
    u16* y = Ybuf + (size_t)row * CONVD;
    const u16* z = Z + (size_t)row * DINNER;

    ushort4 yv = *(const ushort4*)(y + t*4);
    ushort4 zv = *(const ushort4*)(z + t*4);
    float v[4]; float ss = 0.f;
    #pragma unroll
    for (int j = 0; j < 4; ++j) {
        const float zz = bf2f(((const u16*)&zv)[j]);
        const float vv = bf2f(((const u16*)&yv)[j]) * siluf(zz);
        v[j] = vv; ss += vv*vv;
    }
    #pragma unroll
    for (int o = 32; o > 0; o >>= 1) ss += __shfl_down(ss, o);
    __shared__ float wsum[4];
    if ((t & 63) == 0) wsum[t >> 6] = ss;
    __syncthreads();
    const float total = wsum[0] + wsum[1] + wsum[2] + wsum[3];
    const float scale = rsqrtf(total / (float)DINNER + 1e-5f);
    ushort4 ov;
    #pragma unroll
    for (int j = 0; j < 4; ++j)
        ((u16*)&ov)[j] = f2bf(v[j] * scale * nw[t*4 + j]);
    *(ushort4*)(y + t*4) = ov;
}

// ------------------------------------------------------------------ host ----
extern "C" void kernel_launch(void* const* d_in, const int* in_sizes, int n_in,
                              void* d_out, int out_size, void* d_ws, size_t ws_size,
                              hipStream_t stream)
{
    const float* x        = (const float*)d_in[0];
    const float* gate_w   = (const float*)d_in[1];
    const float* gate_b   = (const float*)d_in[2];
    const float* gate_n   = (const float*)d_in[3];
    const float* in_w     = (const float*)d_in[4];
    const float* conv_w   = (const float*)d_in[5];
    const float* conv_b   = (const float*)d_in[6];
    const float* dt_bias  = (const float*)d_in[7];
    const float* A_log    = (const float*)d_in[8];
    const float* Dskip    = (const float*)d_in[9];
    const float* norm_w   = (const float*)d_in[10];
    const float* out_w    = (const float*)d_in[11];
    float* out = (float*)d_out;

    char* ws = (char*)d_ws;
    // R1 serves sequentially: XBCraw bf16 (gemm->conv) -> Hend (ssd1->ssd2)
    //                         -> Ztile bf16 full-M (z-gemm->norm)
    u16*   R1     = (u16*)ws;                        // 20,480,000 B
    u16*   XCONV  = (u16*)(ws + 20480000);           // 20,480,000 B
    u16*   xbf    = (u16*)(ws + 40960000);           //  8,192,000 B
    u16*   inwb   = (u16*)(ws + 49152000);           //  9,437,184 B
    u16*   outwb  = (u16*)(ws + 58589184);           //  4,194,304 B
    float* DTb    = (float*)(ws + 62783488);         //    512,000 B
    float* Acum   = (float*)(ws + 63295488);         //    512,000 B
    float* cbuf   = (float*)(ws + 63807488);         //      4,096 B
    float* maskb  = (float*)(ws + 63811584);         //    128,000 B
    u16*   dtw    = (u16*)(ws + 63939584);           //    524,288 B (4x128x512)
    // total 64,463,872 B (< 74.36 MB proven-safe)

    gate_kernel<<<M_TOK, 64, 0, stream>>>(x, gate_w, gate_b, gate_n, maskb);
    // one-time bf16 conversions
    cvt_kernel<<<2000, 256, 0, stream>>>(x, xbf, 512000);
    for (int e = 0; e < NEXP; ++e)
        cvt_kernel<<<576, 256, 0, stream>>>(
            in_w + (size_t)e*DIN_ALL*DMODEL, inwb + (size_t)e*2304*512, 147456);
    cvt_kernel<<<1024, 256, 0, stream>>>(out_w, outwb, 262144);
    zero_kernel<<<128, 256, 0, stream>>>(dtw, 32768);
    for (int e = 0; e < NEXP; ++e)
        cvt_kernel<<<4, 256, 0, stream>>>(
            in_w + (size_t)e*DIN_ALL*DMODEL + (size_t)2304*DMODEL,
            dtw + (size_t)e*128*512, 1024);

    for (int e = 0; e < NEXP; ++e) {
        const u16* Wxbc = inwb + (size_t)e*2304*512 + (size_t)1024*512;
        const u16* Wz   = inwb + (size_t)e*2304*512;
        // raw xBC (bf16)
        gemm_bb<0><<<dim3(10, 63), 256, 0, stream>>>(
            xbf, DMODEL, M_TOK, Wxbc, DMODEL, R1, CONVD, nullptr, 0, 0);
        // dt via MFMA + softplus epilogue (cols < 16)
        gemm_bb<3><<<dim3(1, 63), 256, 0, stream>>>(
            xbf, DMODEL, M_TOK, dtw + (size_t)e*128*512, DMODEL,
            DTb, NH, dt_bias + e*NH, 0, 0);
        conv_kernel<<<5000, 256, 0, stream>>>(R1, XCONV, conv_w, conv_b, e);
        ssd1_kernel<<<dim3(NC, NH, BATCH), 512, 0, stream>>>(
            XCONV, DTb, Acum, (u16*)R1, cbuf, A_log, Dskip, e);
        prop_kernel<<<BATCH*NH, 256, 0, stream>>>((u16*)R1, cbuf);
        ssd2_kernel<<<dim3(NC, NH, BATCH), 256, 0, stream>>>(
            XCONV, Acum, (const u16*)R1);
        // z (bf16, full M) into R1 (Hend now dead)
        gemm_bb<0><<<dim3(8, 63), 256, 0, stream>>>(
            xbf, DMODEL, M_TOK, Wz, DMODEL, R1, DINNER, nullptr, 0, 0);
        norm_kernel<<<M_TOK, 256, 0, stream>>>(
            XCONV, R1, norm_w + (size_t)e*DINNER);
        gemm_bb<2><<<dim3(4, 63), 256, 0, stream>>>(
            XCONV, CONVD, M_TOK, outwb + (size_t)e*DMODEL*DINNER, DINNER,
            out, 512, maskb, e, e == 0 ? 1 : 0);
    }
}